// Round 10
// baseline (345.282 us; speedup 1.0000x reference)
//
#include <hip/hip_runtime.h>
#include <math.h>
#include <type_traits>

typedef unsigned short u16;
typedef __attribute__((ext_vector_type(8))) short bf16x8;
typedef __attribute__((ext_vector_type(4))) float f32x4;

// Problem constants (fixed by the reference)
#define B_  2
#define S_  2048
#define D_  2048
#define H_  16
#define HD_ 128
#define L_  512
constexpr float EPS   = 1e-5f;
constexpr float SCALE = 0.08838834764831845f;           // 1/sqrt(128)
constexpr float SCALE_L2E = 0.12751701840172524f;       // SCALE * log2(e)
constexpr float SHIFT2    = -11.541560327111707f;       // -8 * log2(e)

__device__ __forceinline__ u16 f2bf(float x) {
    unsigned u = __float_as_uint(x);
    u += 0x7fffu + ((u >> 16) & 1u);   // round-to-nearest-even
    return (u16)(u >> 16);
}
__device__ __forceinline__ float bf2f(u16 v) {
    return __uint_as_float(((unsigned)v) << 16);
}

// async global->LDS, 16 B per lane; LDS dest = lptr + lane*16 (wave-uniform base)
__device__ __forceinline__ void gl_lds16(const u16* g, u16* l) {
    __builtin_amdgcn_global_load_lds(
        (const __attribute__((address_space(1))) unsigned int*)g,
        (__attribute__((address_space(3))) unsigned int*)l, 16, 0, 0);
}

// ---------------------------------------------------------------------------
// bf16 MFMA GEMM (m97 structure): C[M,N] = A[M,K] @ Bt[N,K]^T + bias[N]
// BM=128 x BN tile, BK=32, 256 thr, 4 waves (2x2), per-wave 64 x BN/2.
// BN=64 where the BN=128 grid would leave the GPU under-occupied (down-proj
// N=1024: 512 wgs; out-proj N=2048: 1024 wgs = 4 blk/CU vs 2 grid-capped at
// BN=128 -- same R6 lever, m114 wave-overlap is the latency-hiding mechanism).
// lda/ldc: A/C row strides.  Bias: n < nsplit ? biasA[n] : biasB[n-nsplit].
// ---------------------------------------------------------------------------
template <typename OutT, int BN>
__global__ __launch_bounds__(256)
void gemm_mfma_kernel(const u16* __restrict__ A, const u16* __restrict__ Bt,
                      const float* __restrict__ biasA,
                      const float* __restrict__ biasB, OutT* __restrict__ C,
                      int M, int N, int K, int lda, int ldc, int nsplit) {
    constexpr int NJ = BN / 32;            // per-wave j-tiles (BN/2 cols / 16)
    __shared__ __align__(16) u16 As[128 * 32];
    __shared__ __align__(16) u16 Bs[BN * 32];

    const int tid  = threadIdx.x;
    const int wave = tid >> 6, lane = tid & 63;
    const int l15  = lane & 15, g = lane >> 4;
    const int wm   = wave >> 1, wn = wave & 1;
    const int m0   = blockIdx.y * 128, n0 = blockIdx.x * BN;

    const int sr = lane >> 2;       // staging row within 16-row group
    const int sc = lane & 3;        // chunk slot
    const int swz = (l15 >> 1) & 3; // read-side swizzle key

    f32x4 acc[4][NJ];
#pragma unroll
    for (int i = 0; i < 4; ++i)
#pragma unroll
        for (int j = 0; j < NJ; ++j) acc[i][j] = (f32x4)0.f;

    for (int k0 = 0; k0 < K; k0 += 32) {
#pragma unroll
        for (int t = 0; t < 2; ++t) {   // A: 128 rows
            const int r  = wave * 32 + t * 16 + sr;
            const int c  = sc ^ ((r >> 1) & 3);
            gl_lds16(A + (size_t)(m0 + r) * lda + k0 + c * 8,
                     &As[(wave * 32 + t * 16) * 32]);
        }
#pragma unroll
        for (int t = 0; t < BN / 64; ++t) {  // B: BN rows
            const int r  = wave * (BN / 4) + t * 16 + sr;
            const int c  = sc ^ ((r >> 1) & 3);
            gl_lds16(Bt + (size_t)(n0 + r) * K + k0 + c * 8,
                     &Bs[(wave * (BN / 4) + t * 16) * 32]);
        }
        __syncthreads();

        bf16x8 af[4], bfr[NJ];
#pragma unroll
        for (int i = 0; i < 4; ++i) {
            const int ra = wm * 64 + i * 16 + l15;
            af[i]  = *(const bf16x8*)&As[ra * 32 + (g ^ swz) * 8];
        }
#pragma unroll
        for (int j = 0; j < NJ; ++j) {
            const int rb = wn * (BN / 2) + j * 16 + l15;
            bfr[j] = *(const bf16x8*)&Bs[rb * 32 + (g ^ swz) * 8];
        }
#pragma unroll
        for (int i = 0; i < 4; ++i)
#pragma unroll
            for (int j = 0; j < NJ; ++j)
                acc[i][j] = __builtin_amdgcn_mfma_f32_16x16x32_bf16(
                    af[i], bfr[j], acc[i][j], 0, 0, 0);
        __syncthreads();
    }

#pragma unroll
    for (int j = 0; j < NJ; ++j) {
        const int n  = n0 + wn * (BN / 2) + j * 16 + l15;
        const float bv = (n < nsplit) ? biasA[n] : biasB[n - nsplit];
#pragma unroll
        for (int i = 0; i < 4; ++i) {
            const int mb = m0 + wm * 64 + i * 16 + g * 4;
#pragma unroll
            for (int r = 0; r < 4; ++r) {
                float v = acc[i][j][r] + bv;
                if constexpr (std::is_same_v<OutT, float>)
                    C[(size_t)(mb + r) * ldc + n] = v;
                else
                    C[(size_t)(mb + r) * ldc + n] = f2bf(v);
            }
        }
    }
}

// ---------------------------------------------------------------------------
// Merged up-projection GEMM (kv-up + q-up in ONE launch). Block-uniform
// dispatch on x: x<32 kv-up (K-half -> k_bf, V-half -> vt transposed);
// x>=32 q-up -> q_bf. Both read lat with lda = 2L.
// ---------------------------------------------------------------------------
__global__ __launch_bounds__(256)
void up_gemm_kernel(const u16* __restrict__ lat,
                    const u16* __restrict__ wkvu_t, const u16* __restrict__ wqu_t,
                    const float* __restrict__ bkv_up, const float* __restrict__ bq_up,
                    u16* __restrict__ k_bf, u16* __restrict__ vt,
                    u16* __restrict__ q_bf) {
    __shared__ __align__(16) u16 As[128 * 32];
    __shared__ __align__(16) u16 Bs[128 * 32];

    const int bx    = blockIdx.x;
    const bool iskv = bx < 32;
    const u16* A    = iskv ? lat + L_ : lat;
    const u16* Bt   = iskv ? wkvu_t : wqu_t;
    const float* bias = iskv ? bkv_up : bq_up;
    const int n0    = (iskv ? bx : bx - 32) * 128;
    const int m0    = blockIdx.y * 128;
    constexpr int K = L_, lda = 2 * L_;

    const int tid  = threadIdx.x;
    const int wave = tid >> 6, lane = tid & 63;
    const int l15  = lane & 15, g = lane >> 4;
    const int wm   = wave >> 1, wn = wave & 1;

    const int sr = lane >> 2;
    const int sc = lane & 3;
    const int swz = (l15 >> 1) & 3;

    f32x4 acc[4][4];
#pragma unroll
    for (int i = 0; i < 4; ++i)
#pragma unroll
        for (int j = 0; j < 4; ++j) acc[i][j] = (f32x4)0.f;

    for (int k0 = 0; k0 < K; k0 += 32) {
#pragma unroll
        for (int t = 0; t < 2; ++t) {
            const int r  = wave * 32 + t * 16 + sr;
            const int c  = sc ^ ((r >> 1) & 3);
            gl_lds16(A  + (size_t)(m0 + r) * lda + k0 + c * 8,
                     &As[(wave * 32 + t * 16) * 32]);
            gl_lds16(Bt + (size_t)(n0 + r) * K + k0 + c * 8,
                     &Bs[(wave * 32 + t * 16) * 32]);
        }
        __syncthreads();

        bf16x8 af[4], bfr[4];
#pragma unroll
        for (int i = 0; i < 4; ++i) {
            const int ra = wm * 64 + i * 16 + l15;
            af[i]  = *(const bf16x8*)&As[ra * 32 + (g ^ swz) * 8];
            const int rb = wn * 64 + i * 16 + l15;
            bfr[i] = *(const bf16x8*)&Bs[rb * 32 + (g ^ swz) * 8];
        }
#pragma unroll
        for (int i = 0; i < 4; ++i)
#pragma unroll
            for (int j = 0; j < 4; ++j)
                acc[i][j] = __builtin_amdgcn_mfma_f32_16x16x32_bf16(
                    af[i], bfr[j], acc[i][j], 0, 0, 0);
        __syncthreads();
    }

    const bool vstore = iskv && (n0 >= D_);   // block-uniform
#pragma unroll
    for (int j = 0; j < 4; ++j) {
        const int n  = n0 + wn * 64 + j * 16 + l15;
        const float bv = bias[n];
        if (vstore) {
            // transposed V store: vt[(b*H+h)*HD+d][s], s = m (4 consecutive)
            const int dg = n - D_;
            const int hh = dg >> 7, dd = dg & 127;
            u16* vrow = vt + ((size_t)(((m0 >> 11) * H_ + hh) * HD_ + dd)) * S_;
#pragma unroll
            for (int i = 0; i < 4; ++i) {
                const int mb = m0 + wm * 64 + i * 16 + g * 4;
                ushort4 o;
                o.x = f2bf(acc[i][j][0] + bv);
                o.y = f2bf(acc[i][j][1] + bv);
                o.z = f2bf(acc[i][j][2] + bv);
                o.w = f2bf(acc[i][j][3] + bv);
                *(ushort4*)&vrow[mb & (S_ - 1)] = o;
            }
        } else {
            u16* C = iskv ? k_bf : q_bf;
#pragma unroll
            for (int i = 0; i < 4; ++i) {
                const int mb = m0 + wm * 64 + i * 16 + g * 4;
#pragma unroll
                for (int r = 0; r < 4; ++r)
                    C[(size_t)(mb + r) * D_ + n] = f2bf(acc[i][j][r] + bv);
            }
        }
    }
}

// ---------------------------------------------------------------------------
// Prep: all 5 weight transposes + x fp32->bf16 cast in ONE launch.
// ---------------------------------------------------------------------------
__global__ __launch_bounds__(256)
void prep_kernel(const float* __restrict__ wqd,  const float* __restrict__ wkvd,
                 const float* __restrict__ wqu,  const float* __restrict__ wkvu,
                 const float* __restrict__ wo,   const float* __restrict__ x,
                 u16* __restrict__ wd_t,  u16* __restrict__ wqu_t,
                 u16* __restrict__ wkvu_t, u16* __restrict__ wout_t,
                 u16* __restrict__ x_bf) {
    int bid = blockIdx.x;
    if (bid >= 2304) {   // x cast: 8192 blocks x 256 thr x float4
        const int i = (bid - 2304) * 256 + threadIdx.x;
        float4 f = ((const float4*)x)[i];
        ushort4 o;
        o.x = f2bf(f.x); o.y = f2bf(f.y); o.z = f2bf(f.z); o.w = f2bf(f.w);
        ((ushort4*)x_bf)[i] = o;
        return;
    }
    const float* W; u16* Wt; int K, N;
    if (bid < 256)       { W = wqd;  Wt = wd_t;                      K = 2048; N = 512; }
    else if (bid < 512)  { W = wkvd; Wt = wd_t + (size_t)512 * 2048; K = 2048; N = 512;  bid -= 256; }
    else if (bid < 768)  { W = wqu;  Wt = wqu_t;                     K = 512;  N = 2048; bid -= 512; }
    else if (bid < 1280) { W = wkvu; Wt = wkvu_t;                    K = 512;  N = 4096; bid -= 768; }
    else                 { W = wo;   Wt = wout_t;                    K = 2048; N = 2048; bid -= 1280; }
    const int nblk = N / 64;
    const int n0 = (bid % nblk) * 64, k0 = (bid / nblk) * 64;

    __shared__ u16 T[64][72];
    const int t = threadIdx.x;
    {
        const int kr = t >> 2, nc = (t & 3) * 16;
#pragma unroll
        for (int v = 0; v < 4; ++v) {
            float4 f = *(const float4*)&W[(size_t)(k0 + kr) * N + n0 + nc + v * 4];
            T[nc + v * 4 + 0][kr] = f2bf(f.x);
            T[nc + v * 4 + 1][kr] = f2bf(f.y);
            T[nc + v * 4 + 2][kr] = f2bf(f.z);
            T[nc + v * 4 + 3][kr] = f2bf(f.w);
        }
    }
    __syncthreads();
    {
        const int nr = t >> 2, kc = (t & 3) * 16;
        union { u16 u[16]; uint4 q[2]; } o;
#pragma unroll
        for (int i = 0; i < 16; ++i) o.u[i] = T[nr][kc + i];
        uint4* dst = (uint4*)&Wt[(size_t)(n0 + nr) * K + k0 + kc];
        dst[0] = o.q[0]; dst[1] = o.q[1];
    }
}

// ---------------------------------------------------------------------------
// In-place bf16 row LayerNorm over the fused latent [M][1024].
// ---------------------------------------------------------------------------
__global__ __launch_bounds__(256)
void layernorm_fused_kernel(u16* __restrict__ buf,
                            const float* __restrict__ gq,
                            const float* __restrict__ bq,
                            const float* __restrict__ gkv,
                            const float* __restrict__ bkv) {
    const int r    = blockIdx.x;
    const int half = r & 1;
    u16* p = buf + (size_t)(r >> 1) * 1024 + half * 512;
    const float* g    = half ? gkv : gq;
    const float* bvec = half ? bkv : bq;
    const int tid = threadIdx.x;

    float x0 = bf2f(p[tid]), x1 = bf2f(p[tid + 256]);
    float s  = x0 + x1;
    float sq = x0 * x0 + x1 * x1;

    __shared__ float red[8];
    __shared__ float stats[2];

#pragma unroll
    for (int off = 32; off; off >>= 1) {
        s  += __shfl_down(s, off);
        sq += __shfl_down(sq, off);
    }
    const int wave = tid >> 6;
    if ((tid & 63) == 0) { red[wave] = s; red[wave + 4] = sq; }
    __syncthreads();
    if (tid == 0) {
        float ts = red[0] + red[1] + red[2] + red[3];
        float tq = red[4] + red[5] + red[6] + red[7];
        float mean = ts / (float)L_;
        float var  = tq / (float)L_ - mean * mean;
        stats[0] = mean;
        stats[1] = rsqrtf(var + EPS);
    }
    __syncthreads();
    const float mean = stats[0], rstd = stats[1];
    p[tid]       = f2bf((x0 - mean) * rstd * g[tid]       + bvec[tid]);
    p[tid + 256] = f2bf((x1 - mean) * rstd * g[tid + 256] + bvec[tid + 256]);
}

// ---------------------------------------------------------------------------
// Flash attention v11 = v9 structure (measured best: 71.8us) + exp2 folding.
// R9 post-mortem: the 3-blocks/CU LDS-diet (v10) FAILED on HW -- occupancy
// counter flat at ~20 despite LDS 54272<=54613, and the extra mid-tile
// barrier (V single-buffered) cost 5%: 71.8 -> 75.5us. Reverted to the
// single-barrier, K+V double-buffered 73KB layout. Kept from v10: exp2
// folding (P = exp2(fma(s, SCALE*log2e, -8*log2e)) -- v_exp_f32 is 2^x
// natively; saves 16 v_mul/tile vs __expf).
// LDS: 32KB Kdbuf + 32KB Vdbuf + 9KB Pl = 73KB -> 2 blocks/CU.
// grid: (S/64)*H*B = 1024 blocks, heavy q-groups first.
// ---------------------------------------------------------------------------
#define PPITCH 72

__global__ __launch_bounds__(256)
void flash_attn_kernel(const u16* __restrict__ qbf, const u16* __restrict__ kbf,
                       const u16* __restrict__ vt,
                       const unsigned char* __restrict__ mask,
                       u16* __restrict__ out) {
    const int x    = blockIdx.x;
    const int qgrp = (S_ / 64 - 1) - (x >> 5);   // heavy blocks first
    const int hb   = x & 31;
    const int h    = hb >> 1, b = hb & 1;
    const int tid  = threadIdx.x;
    const int wave = tid >> 6, lane = tid & 63;
    const int l15  = lane & 15, g = lane >> 4;
    const int q0   = qgrp * 64 + wave * 16;      // this wave's 16 queries

    __shared__ __align__(16) u16 Ks[2][64][128];   // 2 x 16 KB, key x d
    __shared__ __align__(16) u16 Vs[2][128][64];   // 2 x 16 KB, d x key
    __shared__ __align__(16) u16 Pl[4][16][PPITCH];

    const u16* kbase = kbf + (size_t)b * S_ * D_ + h * HD_;
    const u16* vbase = vt + (size_t)((b * H_ + h) * HD_) * S_;
    const unsigned char* mbase = mask + b * S_;

    const int kr_l = lane >> 4;          // K: row within 4-row chunk
    const int kb_l = (lane & 15) * 16;   // K: byte within 256B row
    const int vr_l = lane >> 3;          // V: row within 8-row chunk
    const int vb_l = (lane & 7) * 16;    // V: byte within 128B row

    auto STAGE = [&](int bi, int k0s) {
#pragma unroll
        for (int j = 0; j < 4; ++j) {
            const int rr = wave * 16 + j * 4 + kr_l;          // key row 0..63
            gl_lds16(kbase + (size_t)(k0s + rr) * D_ +
                         ((kb_l ^ ((rr & 7) << 4)) >> 1),
                     &Ks[bi][wave * 16 + j * 4][0]);
            const int rv = wave * 32 + j * 8 + vr_l;          // d row 0..127
            gl_lds16(vbase + (size_t)rv * S_ + k0s +
                         ((vb_l ^ ((rv & 7) << 4)) >> 1),
                     &Vs[bi][wave * 32 + j * 8][0]);
        }
    };

    // Q fragments (A-operand): row l15, k = c*32 + g*8 + j
    bf16x8 qf[4];
#pragma unroll
    for (int c = 0; c < 4; ++c)
        qf[c] = *(const bf16x8*)(qbf +
            (size_t)(b * S_ + q0 + l15) * D_ + h * HD_ + c * 32 + g * 8);

    // all-ones bf16 B-fragment for the row-sum MFMA
    bf16x8 ones;
#pragma unroll
    for (int j = 0; j < 8; ++j) ones[j] = (short)0x3f80;  // 1.0f in bf16

    f32x4 o[8];
#pragma unroll
    for (int i = 0; i < 8; ++i) o[i] = (f32x4)0.f;
    f32x4 osum = (f32x4)0.f;

    const int qb  = q0 + 4 * g;
    const int ksw = (l15 & 7) << 4;        // read-side XOR key (bytes)
    const int nt  = qgrp + 1;              // uniform across the block

    STAGE(0, 0);
    __syncthreads();   // implicit vmcnt(0) drain before s_barrier

    for (int kt = 0; kt < nt; ++kt) {
        const int k0  = kt * 64;
        const int cur = kt & 1;
        if (kt + 1 < nt) STAGE(cur ^ 1, k0 + 64);   // prefetch next tile

        // padding mask -> additive bias (static shift -8, exp2 domain)
        float nb[4];
#pragma unroll
        for (int cc = 0; cc < 4; ++cc)
            nb[cc] = mbase[k0 + cc * 16 + l15] ? -INFINITY : SHIFT2;

        // QK^T from LDS: 4 independent accumulation chains of 4 MFMAs
        f32x4 s[4];
#pragma unroll
        for (int cc = 0; cc < 4; ++cc) {
            bf16x8 kf[4];
#pragma unroll
            for (int c = 0; c < 4; ++c)
                kf[c] = *(const bf16x8*)&Ks[cur][cc * 16 + l15]
                    [((c * 64 + g * 16) ^ ksw) >> 1];
            f32x4 t = (f32x4)0.f;
#pragma unroll
            for (int c = 0; c < 4; ++c)
                t = __builtin_amdgcn_mfma_f32_16x16x32_bf16(qf[c], kf[c], t, 0, 0, 0);
            s[cc] = t;
        }

        // scale + shift/padding in one FMA per score (exp2 domain)
#pragma unroll
        for (int cc = 0; cc < 4; ++cc)
#pragma unroll
            for (int r = 0; r < 4; ++r)
                s[cc][r] = fmaf(s[cc][r], SCALE_L2E, nb[cc]);

        // causal mask: only the final tile contains keys > query
        if (kt == nt - 1) {
#pragma unroll
            for (int cc = 0; cc < 4; ++cc) {
                const int kk = k0 + cc * 16 + l15;
#pragma unroll
                for (int r = 0; r < 4; ++r)
                    if (kk > qb + r) s[cc][r] = -INFINITY;
            }
        }

        // P = exp2(s): C-layout -> LDS -> A-layout (no max, no rescale)
#pragma unroll
        for (int cc = 0; cc < 4; ++cc)
#pragma unroll
            for (int r = 0; r < 4; ++r)
                Pl[wave][4 * g + r][cc * 16 + l15] = f2bf(exp2f(s[cc][r]));

        const bf16x8 pf0 = *(const bf16x8*)&Pl[wave][l15][g * 8];
        const bf16x8 pf1 = *(const bf16x8*)&Pl[wave][l15][32 + g * 8];

        // PV from LDS over 64 keys + ones-column row-sum accumulation
#pragma unroll
        for (int i = 0; i < 8; ++i) {
            bf16x8 vf0 = *(const bf16x8*)&Vs[cur][16 * i + l15]
                [((g * 16) ^ ksw) >> 1];
            bf16x8 vf1 = *(const bf16x8*)&Vs[cur][16 * i + l15]
                [((g * 16 + 64) ^ ksw) >> 1];
            o[i] = __builtin_amdgcn_mfma_f32_16x16x32_bf16(pf0, vf0, o[i], 0, 0, 0);
            o[i] = __builtin_amdgcn_mfma_f32_16x16x32_bf16(pf1, vf1, o[i], 0, 0, 0);
        }
        osum = __builtin_amdgcn_mfma_f32_16x16x32_bf16(pf0, ones, osum, 0, 0, 0);
        osum = __builtin_amdgcn_mfma_f32_16x16x32_bf16(pf1, ones, osum, 0, 0, 0);

        __syncthreads();   // drains prefetch (vmcnt(0)) + WAR on buf[cur]
    }

    // epilogue: normalize by osum (row-sum of bf16 P, same rows as o) + store
    float inv[4];
#pragma unroll
    for (int r = 0; r < 4; ++r) inv[r] = 1.0f / osum[r];
#pragma unroll
    for (int i = 0; i < 8; ++i)
#pragma unroll
        for (int r = 0; r < 4; ++r)
            out[(size_t)(b * S_ + q0 + 4 * g + r) * D_ +
                h * HD_ + 16 * i + l15] = f2bf(o[i][r] * inv[r]);
}

// ---------------------------------------------------------------------------
extern "C" void kernel_launch(void* const* d_in, const int* in_sizes, int n_in,
                              void* d_out, int out_size, void* d_ws, size_t ws_size,
                              hipStream_t stream) {
    const float* x        = (const float*)d_in[0];
    const unsigned char* mask = (const unsigned char*)d_in[1];
    const float* wq_down  = (const float*)d_in[2];
    const float* bq_down  = (const float*)d_in[3];
    const float* gq_ln    = (const float*)d_in[4];
    const float* bq_ln    = (const float*)d_in[5];
    const float* wq_up    = (const float*)d_in[6];
    const float* bq_up    = (const float*)d_in[7];
    const float* wkv_down = (const float*)d_in[8];
    const float* bkv_down = (const float*)d_in[9];
    const float* gkv_ln   = (const float*)d_in[10];
    const float* bkv_ln   = (const float*)d_in[11];
    const float* wkv_up   = (const float*)d_in[12];
    const float* bkv_up   = (const float*)d_in[13];
    const float* w_out    = (const float*)d_in[14];
    const float* b_out    = (const float*)d_in[15];
    float* out = (float*)d_out;

    // Workspace layout (byte offsets, MB). Total 90 MB.
    //  0-16 : x_bf (dead after down-GEMM) / vt (written by up-GEMM V-epilogue)
    // 16-24 : lat fused [4096][1024] bf16 (dead after up-GEMMs)
    // 16-32 : attn_bf (written by flash; overlays lat + wd_t + wkvu_t, all dead)
    // 24-28 : wd_t fused [1024][2048]
    // 28-32 : wkvu_t   32-34 : wqu_t   34-42 : wout_t
    // 42-58 : q_bf     58-74 : k_bf [4096][2048] (compact K, V fused to vt)
    char* ws = (char*)d_ws;
    u16* x_bf    = (u16*)(ws);
    u16* vt      = (u16*)(ws);
    u16* lat     = (u16*)(ws + (16u << 20));
    u16* attn_bf = (u16*)(ws + (16u << 20));
    u16* wd_t    = (u16*)(ws + (24u << 20));
    u16* wkvu_t  = (u16*)(ws + (28u << 20));
    u16* wqu_t   = (u16*)(ws + (32u << 20));
    u16* wout_t  = (u16*)(ws + (34u << 20));
    u16* q_bf    = (u16*)(ws + (42u << 20));
    u16* k_bf    = (u16*)(ws + (58u << 20));

    const int M = B_ * S_;  // 4096
    dim3 blk(256);

    // prep: x cast + all 5 weight transposes in one launch
    prep_kernel<<<10496, blk, 0, stream>>>(
        wq_down, wkv_down, wq_up, wkv_up, w_out, x,
        wd_t, wqu_t, wkvu_t, wout_t, x_bf);

    // fused down-projection: [M,2048] @ [2048,1024] -> lat (q | kv), BN=64
    gemm_mfma_kernel<u16, 64><<<dim3((2 * L_) / 64, M / 128), blk, 0, stream>>>(
        x_bf, wd_t, bq_down, bkv_down, lat,
        M, 2 * L_, D_, D_, 2 * L_, L_);

    // fused LayerNorm over both halves
    layernorm_fused_kernel<<<2 * M, blk, 0, stream>>>(lat, gq_ln, bq_ln, gkv_ln, bkv_ln);

    // merged up-projections: kv-up (with fused V transpose) + q-up
    up_gemm_kernel<<<dim3(48, M / 128), blk, 0, stream>>>(
        lat, wkvu_t, wqu_t, bkv_up, bq_up, k_bf, vt, q_bf);

    // Flash attention v11 -> bf16 attn
    flash_attn_kernel<<<dim3((S_ / 64) * H_ * B_), blk, 0, stream>>>(
        q_bf, k_bf, vt, mask, attn_bf);

    // Output projection (fp32 out), BN=64: 1024 wgs = 4 blk/CU (was 512/2)
    gemm_mfma_kernel<float, 64><<<dim3(D_ / 64, M / 128), blk, 0, stream>>>(
        attn_bf, wout_t, b_out, b_out, out,
        M, D_, D_, D_, D_, D_);
}

// Round 11
// 335.342 us; speedup vs baseline: 1.0296x; 1.0296x over previous
//
#include <hip/hip_runtime.h>
#include <math.h>
#include <type_traits>

typedef unsigned short u16;
typedef __attribute__((ext_vector_type(8))) short bf16x8;
typedef __attribute__((ext_vector_type(4))) float f32x4;

// Problem constants (fixed by the reference)
#define B_  2
#define S_  2048
#define D_  2048
#define H_  16
#define HD_ 128
#define L_  512
constexpr float EPS   = 1e-5f;
constexpr float SCALE = 0.08838834764831845f;           // 1/sqrt(128)

// Static-softmax score transform. R10 lesson: exp2f() is libm-precise (NOT
// v_exp_f32) and cost +8pts VALUBusy. Use the raw HW exp2 builtin when
// available (v_exp_f32 IS 2^x; exp2(-inf)=0 handles masked keys); otherwise
// fall back to the exact v9 __expf path (proven 71.8us).
#if __has_builtin(__builtin_amdgcn_exp2f)
constexpr float SCORE_SCALE = 0.12751701840172524f;  // SCALE * log2(e)
constexpr float SCORE_SHIFT = -11.541560327111707f;  // -8 * log2(e)
__device__ __forceinline__ float expx(float x) { return __builtin_amdgcn_exp2f(x); }
#else
constexpr float SCORE_SCALE = 0.08838834764831845f;
constexpr float SCORE_SHIFT = -8.0f;
__device__ __forceinline__ float expx(float x) { return __expf(x); }
#endif

__device__ __forceinline__ u16 f2bf(float x) {
    unsigned u = __float_as_uint(x);
    u += 0x7fffu + ((u >> 16) & 1u);   // round-to-nearest-even
    return (u16)(u >> 16);
}
__device__ __forceinline__ float bf2f(u16 v) {
    return __uint_as_float(((unsigned)v) << 16);
}

// async global->LDS, 16 B per lane; LDS dest = lptr + lane*16 (wave-uniform base)
__device__ __forceinline__ void gl_lds16(const u16* g, u16* l) {
    __builtin_amdgcn_global_load_lds(
        (const __attribute__((address_space(1))) unsigned int*)g,
        (__attribute__((address_space(3))) unsigned int*)l, 16, 0, 0);
}

// ---------------------------------------------------------------------------
// bf16 MFMA GEMM (m97 structure): C[M,N] = A[M,K] @ Bt[N,K]^T + bias[N]
// BM=128 x BN tile, BK=32, 256 thr, 4 waves (2x2), per-wave 64 x BN/2.
// BN rule (R6/R10 A-B): 1 blk/CU -> use BN=64 (big win, down-proj);
// already 2 blk/CU -> keep BN=128 (BN=64 trades MFMA:stage ratio for
// occupancy at a net LOSS -- R10 out-GEMM regression). 2 blk/CU is this
// structure's sweet spot.
// lda/ldc: A/C row strides.  Bias: n < nsplit ? biasA[n] : biasB[n-nsplit].
// ---------------------------------------------------------------------------
template <typename OutT, int BN>
__global__ __launch_bounds__(256)
void gemm_mfma_kernel(const u16* __restrict__ A, const u16* __restrict__ Bt,
                      const float* __restrict__ biasA,
                      const float* __restrict__ biasB, OutT* __restrict__ C,
                      int M, int N, int K, int lda, int ldc, int nsplit) {
    constexpr int NJ = BN / 32;            // per-wave j-tiles (BN/2 cols / 16)
    __shared__ __align__(16) u16 As[128 * 32];
    __shared__ __align__(16) u16 Bs[BN * 32];

    const int tid  = threadIdx.x;
    const int wave = tid >> 6, lane = tid & 63;
    const int l15  = lane & 15, g = lane >> 4;
    const int wm   = wave >> 1, wn = wave & 1;
    const int m0   = blockIdx.y * 128, n0 = blockIdx.x * BN;

    const int sr = lane >> 2;       // staging row within 16-row group
    const int sc = lane & 3;        // chunk slot
    const int swz = (l15 >> 1) & 3; // read-side swizzle key

    f32x4 acc[4][NJ];
#pragma unroll
    for (int i = 0; i < 4; ++i)
#pragma unroll
        for (int j = 0; j < NJ; ++j) acc[i][j] = (f32x4)0.f;

    for (int k0 = 0; k0 < K; k0 += 32) {
#pragma unroll
        for (int t = 0; t < 2; ++t) {   // A: 128 rows
            const int r  = wave * 32 + t * 16 + sr;
            const int c  = sc ^ ((r >> 1) & 3);
            gl_lds16(A + (size_t)(m0 + r) * lda + k0 + c * 8,
                     &As[(wave * 32 + t * 16) * 32]);
        }
#pragma unroll
        for (int t = 0; t < BN / 64; ++t) {  // B: BN rows
            const int r  = wave * (BN / 4) + t * 16 + sr;
            const int c  = sc ^ ((r >> 1) & 3);
            gl_lds16(Bt + (size_t)(n0 + r) * K + k0 + c * 8,
                     &Bs[(wave * (BN / 4) + t * 16) * 32]);
        }
        __syncthreads();

        bf16x8 af[4], bfr[NJ];
#pragma unroll
        for (int i = 0; i < 4; ++i) {
            const int ra = wm * 64 + i * 16 + l15;
            af[i]  = *(const bf16x8*)&As[ra * 32 + (g ^ swz) * 8];
        }
#pragma unroll
        for (int j = 0; j < NJ; ++j) {
            const int rb = wn * (BN / 2) + j * 16 + l15;
            bfr[j] = *(const bf16x8*)&Bs[rb * 32 + (g ^ swz) * 8];
        }
#pragma unroll
        for (int i = 0; i < 4; ++i)
#pragma unroll
            for (int j = 0; j < NJ; ++j)
                acc[i][j] = __builtin_amdgcn_mfma_f32_16x16x32_bf16(
                    af[i], bfr[j], acc[i][j], 0, 0, 0);
        __syncthreads();
    }

#pragma unroll
    for (int j = 0; j < NJ; ++j) {
        const int n  = n0 + wn * (BN / 2) + j * 16 + l15;
        const float bv = (n < nsplit) ? biasA[n] : biasB[n - nsplit];
#pragma unroll
        for (int i = 0; i < 4; ++i) {
            const int mb = m0 + wm * 64 + i * 16 + g * 4;
#pragma unroll
            for (int r = 0; r < 4; ++r) {
                float v = acc[i][j][r] + bv;
                if constexpr (std::is_same_v<OutT, float>)
                    C[(size_t)(mb + r) * ldc + n] = v;
                else
                    C[(size_t)(mb + r) * ldc + n] = f2bf(v);
            }
        }
    }
}

// ---------------------------------------------------------------------------
// Merged up-projection GEMM (kv-up + q-up in ONE launch). Block-uniform
// dispatch on x: x<32 kv-up (K-half -> k_bf, V-half -> vt transposed);
// x>=32 q-up -> q_bf. Both read lat with lda = 2L.
// ---------------------------------------------------------------------------
__global__ __launch_bounds__(256)
void up_gemm_kernel(const u16* __restrict__ lat,
                    const u16* __restrict__ wkvu_t, const u16* __restrict__ wqu_t,
                    const float* __restrict__ bkv_up, const float* __restrict__ bq_up,
                    u16* __restrict__ k_bf, u16* __restrict__ vt,
                    u16* __restrict__ q_bf) {
    __shared__ __align__(16) u16 As[128 * 32];
    __shared__ __align__(16) u16 Bs[128 * 32];

    const int bx    = blockIdx.x;
    const bool iskv = bx < 32;
    const u16* A    = iskv ? lat + L_ : lat;
    const u16* Bt   = iskv ? wkvu_t : wqu_t;
    const float* bias = iskv ? bkv_up : bq_up;
    const int n0    = (iskv ? bx : bx - 32) * 128;
    const int m0    = blockIdx.y * 128;
    constexpr int K = L_, lda = 2 * L_;

    const int tid  = threadIdx.x;
    const int wave = tid >> 6, lane = tid & 63;
    const int l15  = lane & 15, g = lane >> 4;
    const int wm   = wave >> 1, wn = wave & 1;

    const int sr = lane >> 2;
    const int sc = lane & 3;
    const int swz = (l15 >> 1) & 3;

    f32x4 acc[4][4];
#pragma unroll
    for (int i = 0; i < 4; ++i)
#pragma unroll
        for (int j = 0; j < 4; ++j) acc[i][j] = (f32x4)0.f;

    for (int k0 = 0; k0 < K; k0 += 32) {
#pragma unroll
        for (int t = 0; t < 2; ++t) {
            const int r  = wave * 32 + t * 16 + sr;
            const int c  = sc ^ ((r >> 1) & 3);
            gl_lds16(A  + (size_t)(m0 + r) * lda + k0 + c * 8,
                     &As[(wave * 32 + t * 16) * 32]);
            gl_lds16(Bt + (size_t)(n0 + r) * K + k0 + c * 8,
                     &Bs[(wave * 32 + t * 16) * 32]);
        }
        __syncthreads();

        bf16x8 af[4], bfr[4];
#pragma unroll
        for (int i = 0; i < 4; ++i) {
            const int ra = wm * 64 + i * 16 + l15;
            af[i]  = *(const bf16x8*)&As[ra * 32 + (g ^ swz) * 8];
            const int rb = wn * 64 + i * 16 + l15;
            bfr[i] = *(const bf16x8*)&Bs[rb * 32 + (g ^ swz) * 8];
        }
#pragma unroll
        for (int i = 0; i < 4; ++i)
#pragma unroll
            for (int j = 0; j < 4; ++j)
                acc[i][j] = __builtin_amdgcn_mfma_f32_16x16x32_bf16(
                    af[i], bfr[j], acc[i][j], 0, 0, 0);
        __syncthreads();
    }

    const bool vstore = iskv && (n0 >= D_);   // block-uniform
#pragma unroll
    for (int j = 0; j < 4; ++j) {
        const int n  = n0 + wn * 64 + j * 16 + l15;
        const float bv = bias[n];
        if (vstore) {
            // transposed V store: vt[(b*H+h)*HD+d][s], s = m (4 consecutive)
            const int dg = n - D_;
            const int hh = dg >> 7, dd = dg & 127;
            u16* vrow = vt + ((size_t)(((m0 >> 11) * H_ + hh) * HD_ + dd)) * S_;
#pragma unroll
            for (int i = 0; i < 4; ++i) {
                const int mb = m0 + wm * 64 + i * 16 + g * 4;
                ushort4 o;
                o.x = f2bf(acc[i][j][0] + bv);
                o.y = f2bf(acc[i][j][1] + bv);
                o.z = f2bf(acc[i][j][2] + bv);
                o.w = f2bf(acc[i][j][3] + bv);
                *(ushort4*)&vrow[mb & (S_ - 1)] = o;
            }
        } else {
            u16* C = iskv ? k_bf : q_bf;
#pragma unroll
            for (int i = 0; i < 4; ++i) {
                const int mb = m0 + wm * 64 + i * 16 + g * 4;
#pragma unroll
                for (int r = 0; r < 4; ++r)
                    C[(size_t)(mb + r) * D_ + n] = f2bf(acc[i][j][r] + bv);
            }
        }
    }
}

// ---------------------------------------------------------------------------
// Prep: all 5 weight transposes + x fp32->bf16 cast in ONE launch.
// ---------------------------------------------------------------------------
__global__ __launch_bounds__(256)
void prep_kernel(const float* __restrict__ wqd,  const float* __restrict__ wkvd,
                 const float* __restrict__ wqu,  const float* __restrict__ wkvu,
                 const float* __restrict__ wo,   const float* __restrict__ x,
                 u16* __restrict__ wd_t,  u16* __restrict__ wqu_t,
                 u16* __restrict__ wkvu_t, u16* __restrict__ wout_t,
                 u16* __restrict__ x_bf) {
    int bid = blockIdx.x;
    if (bid >= 2304) {   // x cast: 8192 blocks x 256 thr x float4
        const int i = (bid - 2304) * 256 + threadIdx.x;
        float4 f = ((const float4*)x)[i];
        ushort4 o;
        o.x = f2bf(f.x); o.y = f2bf(f.y); o.z = f2bf(f.z); o.w = f2bf(f.w);
        ((ushort4*)x_bf)[i] = o;
        return;
    }
    const float* W; u16* Wt; int K, N;
    if (bid < 256)       { W = wqd;  Wt = wd_t;                      K = 2048; N = 512; }
    else if (bid < 512)  { W = wkvd; Wt = wd_t + (size_t)512 * 2048; K = 2048; N = 512;  bid -= 256; }
    else if (bid < 768)  { W = wqu;  Wt = wqu_t;                     K = 512;  N = 2048; bid -= 512; }
    else if (bid < 1280) { W = wkvu; Wt = wkvu_t;                    K = 512;  N = 4096; bid -= 768; }
    else                 { W = wo;   Wt = wout_t;                    K = 2048; N = 2048; bid -= 1280; }
    const int nblk = N / 64;
    const int n0 = (bid % nblk) * 64, k0 = (bid / nblk) * 64;

    __shared__ u16 T[64][72];
    const int t = threadIdx.x;
    {
        const int kr = t >> 2, nc = (t & 3) * 16;
#pragma unroll
        for (int v = 0; v < 4; ++v) {
            float4 f = *(const float4*)&W[(size_t)(k0 + kr) * N + n0 + nc + v * 4];
            T[nc + v * 4 + 0][kr] = f2bf(f.x);
            T[nc + v * 4 + 1][kr] = f2bf(f.y);
            T[nc + v * 4 + 2][kr] = f2bf(f.z);
            T[nc + v * 4 + 3][kr] = f2bf(f.w);
        }
    }
    __syncthreads();
    {
        const int nr = t >> 2, kc = (t & 3) * 16;
        union { u16 u[16]; uint4 q[2]; } o;
#pragma unroll
        for (int i = 0; i < 16; ++i) o.u[i] = T[nr][kc + i];
        uint4* dst = (uint4*)&Wt[(size_t)(n0 + nr) * K + k0 + kc];
        dst[0] = o.q[0]; dst[1] = o.q[1];
    }
}

// ---------------------------------------------------------------------------
// In-place bf16 row LayerNorm over the fused latent [M][1024].
// ---------------------------------------------------------------------------
__global__ __launch_bounds__(256)
void layernorm_fused_kernel(u16* __restrict__ buf,
                            const float* __restrict__ gq,
                            const float* __restrict__ bq,
                            const float* __restrict__ gkv,
                            const float* __restrict__ bkv) {
    const int r    = blockIdx.x;
    const int half = r & 1;
    u16* p = buf + (size_t)(r >> 1) * 1024 + half * 512;
    const float* g    = half ? gkv : gq;
    const float* bvec = half ? bkv : bq;
    const int tid = threadIdx.x;

    float x0 = bf2f(p[tid]), x1 = bf2f(p[tid + 256]);
    float s  = x0 + x1;
    float sq = x0 * x0 + x1 * x1;

    __shared__ float red[8];
    __shared__ float stats[2];

#pragma unroll
    for (int off = 32; off; off >>= 1) {
        s  += __shfl_down(s, off);
        sq += __shfl_down(sq, off);
    }
    const int wave = tid >> 6;
    if ((tid & 63) == 0) { red[wave] = s; red[wave + 4] = sq; }
    __syncthreads();
    if (tid == 0) {
        float ts = red[0] + red[1] + red[2] + red[3];
        float tq = red[4] + red[5] + red[6] + red[7];
        float mean = ts / (float)L_;
        float var  = tq / (float)L_ - mean * mean;
        stats[0] = mean;
        stats[1] = rsqrtf(var + EPS);
    }
    __syncthreads();
    const float mean = stats[0], rstd = stats[1];
    p[tid]       = f2bf((x0 - mean) * rstd * g[tid]       + bvec[tid]);
    p[tid + 256] = f2bf((x1 - mean) * rstd * g[tid + 256] + bvec[tid + 256]);
}

// ---------------------------------------------------------------------------
// Flash attention v12 = v9 structure EXACTLY (measured best: 71.8us) with the
// score transform routed through expx(): raw v_exp_f32 via
// __builtin_amdgcn_exp2f when available (exp2 domain, saves 16 v_mul/tile),
// else the exact v9 __expf path. R10's exp2f() libm regression reverted.
// LDS: 32KB Kdbuf + 32KB Vdbuf + 9KB Pl = 73KB -> 2 blocks/CU.
// grid: (S/64)*H*B = 1024 blocks, heavy q-groups first.
// ---------------------------------------------------------------------------
#define PPITCH 72

__global__ __launch_bounds__(256)
void flash_attn_kernel(const u16* __restrict__ qbf, const u16* __restrict__ kbf,
                       const u16* __restrict__ vt,
                       const unsigned char* __restrict__ mask,
                       u16* __restrict__ out) {
    const int x    = blockIdx.x;
    const int qgrp = (S_ / 64 - 1) - (x >> 5);   // heavy blocks first
    const int hb   = x & 31;
    const int h    = hb >> 1, b = hb & 1;
    const int tid  = threadIdx.x;
    const int wave = tid >> 6, lane = tid & 63;
    const int l15  = lane & 15, g = lane >> 4;
    const int q0   = qgrp * 64 + wave * 16;      // this wave's 16 queries

    __shared__ __align__(16) u16 Ks[2][64][128];   // 2 x 16 KB, key x d
    __shared__ __align__(16) u16 Vs[2][128][64];   // 2 x 16 KB, d x key
    __shared__ __align__(16) u16 Pl[4][16][PPITCH];

    const u16* kbase = kbf + (size_t)b * S_ * D_ + h * HD_;
    const u16* vbase = vt + (size_t)((b * H_ + h) * HD_) * S_;
    const unsigned char* mbase = mask + b * S_;

    const int kr_l = lane >> 4;          // K: row within 4-row chunk
    const int kb_l = (lane & 15) * 16;   // K: byte within 256B row
    const int vr_l = lane >> 3;          // V: row within 8-row chunk
    const int vb_l = (lane & 7) * 16;    // V: byte within 128B row

    auto STAGE = [&](int bi, int k0s) {
#pragma unroll
        for (int j = 0; j < 4; ++j) {
            const int rr = wave * 16 + j * 4 + kr_l;          // key row 0..63
            gl_lds16(kbase + (size_t)(k0s + rr) * D_ +
                         ((kb_l ^ ((rr & 7) << 4)) >> 1),
                     &Ks[bi][wave * 16 + j * 4][0]);
            const int rv = wave * 32 + j * 8 + vr_l;          // d row 0..127
            gl_lds16(vbase + (size_t)rv * S_ + k0s +
                         ((vb_l ^ ((rv & 7) << 4)) >> 1),
                     &Vs[bi][wave * 32 + j * 8][0]);
        }
    };

    // Q fragments (A-operand): row l15, k = c*32 + g*8 + j
    bf16x8 qf[4];
#pragma unroll
    for (int c = 0; c < 4; ++c)
        qf[c] = *(const bf16x8*)(qbf +
            (size_t)(b * S_ + q0 + l15) * D_ + h * HD_ + c * 32 + g * 8);

    // all-ones bf16 B-fragment for the row-sum MFMA
    bf16x8 ones;
#pragma unroll
    for (int j = 0; j < 8; ++j) ones[j] = (short)0x3f80;  // 1.0f in bf16

    f32x4 o[8];
#pragma unroll
    for (int i = 0; i < 8; ++i) o[i] = (f32x4)0.f;
    f32x4 osum = (f32x4)0.f;

    const int qb  = q0 + 4 * g;
    const int ksw = (l15 & 7) << 4;        // read-side XOR key (bytes)
    const int nt  = qgrp + 1;              // uniform across the block

    STAGE(0, 0);
    __syncthreads();   // implicit vmcnt(0) drain before s_barrier

    for (int kt = 0; kt < nt; ++kt) {
        const int k0  = kt * 64;
        const int cur = kt & 1;
        if (kt + 1 < nt) STAGE(cur ^ 1, k0 + 64);   // prefetch next tile

        // padding mask -> additive bias (static shift, or -inf)
        float nb[4];
#pragma unroll
        for (int cc = 0; cc < 4; ++cc)
            nb[cc] = mbase[k0 + cc * 16 + l15] ? -INFINITY : SCORE_SHIFT;

        // QK^T from LDS: 4 independent accumulation chains of 4 MFMAs
        f32x4 s[4];
#pragma unroll
        for (int cc = 0; cc < 4; ++cc) {
            bf16x8 kf[4];
#pragma unroll
            for (int c = 0; c < 4; ++c)
                kf[c] = *(const bf16x8*)&Ks[cur][cc * 16 + l15]
                    [((c * 64 + g * 16) ^ ksw) >> 1];
            f32x4 t = (f32x4)0.f;
#pragma unroll
            for (int c = 0; c < 4; ++c)
                t = __builtin_amdgcn_mfma_f32_16x16x32_bf16(qf[c], kf[c], t, 0, 0, 0);
            s[cc] = t;
        }

        // scale + shift/padding in one FMA per score
#pragma unroll
        for (int cc = 0; cc < 4; ++cc)
#pragma unroll
            for (int r = 0; r < 4; ++r)
                s[cc][r] = fmaf(s[cc][r], SCORE_SCALE, nb[cc]);

        // causal mask: only the final tile contains keys > query
        if (kt == nt - 1) {
#pragma unroll
            for (int cc = 0; cc < 4; ++cc) {
                const int kk = k0 + cc * 16 + l15;
#pragma unroll
                for (int r = 0; r < 4; ++r)
                    if (kk > qb + r) s[cc][r] = -INFINITY;
            }
        }

        // P = expx(s): C-layout -> LDS -> A-layout (no max, no rescale)
#pragma unroll
        for (int cc = 0; cc < 4; ++cc)
#pragma unroll
            for (int r = 0; r < 4; ++r)
                Pl[wave][4 * g + r][cc * 16 + l15] = f2bf(expx(s[cc][r]));

        const bf16x8 pf0 = *(const bf16x8*)&Pl[wave][l15][g * 8];
        const bf16x8 pf1 = *(const bf16x8*)&Pl[wave][l15][32 + g * 8];

        // PV from LDS over 64 keys + ones-column row-sum accumulation
#pragma unroll
        for (int i = 0; i < 8; ++i) {
            bf16x8 vf0 = *(const bf16x8*)&Vs[cur][16 * i + l15]
                [((g * 16) ^ ksw) >> 1];
            bf16x8 vf1 = *(const bf16x8*)&Vs[cur][16 * i + l15]
                [((g * 16 + 64) ^ ksw) >> 1];
            o[i] = __builtin_amdgcn_mfma_f32_16x16x32_bf16(pf0, vf0, o[i], 0, 0, 0);
            o[i] = __builtin_amdgcn_mfma_f32_16x16x32_bf16(pf1, vf1, o[i], 0, 0, 0);
        }
        osum = __builtin_amdgcn_mfma_f32_16x16x32_bf16(pf0, ones, osum, 0, 0, 0);
        osum = __builtin_amdgcn_mfma_f32_16x16x32_bf16(pf1, ones, osum, 0, 0, 0);

        __syncthreads();   // drains prefetch (vmcnt(0)) + WAR on buf[cur]
    }

    // epilogue: normalize by osum (row-sum of bf16 P, same rows as o) + store
    float inv[4];
#pragma unroll
    for (int r = 0; r < 4; ++r) inv[r] = 1.0f / osum[r];
#pragma unroll
    for (int i = 0; i < 8; ++i)
#pragma unroll
        for (int r = 0; r < 4; ++r)
            out[(size_t)(b * S_ + q0 + 4 * g + r) * D_ +
                h * HD_ + 16 * i + l15] = f2bf(o[i][r] * inv[r]);
}

// ---------------------------------------------------------------------------
extern "C" void kernel_launch(void* const* d_in, const int* in_sizes, int n_in,
                              void* d_out, int out_size, void* d_ws, size_t ws_size,
                              hipStream_t stream) {
    const float* x        = (const float*)d_in[0];
    const unsigned char* mask = (const unsigned char*)d_in[1];
    const float* wq_down  = (const float*)d_in[2];
    const float* bq_down  = (const float*)d_in[3];
    const float* gq_ln    = (const float*)d_in[4];
    const float* bq_ln    = (const float*)d_in[5];
    const float* wq_up    = (const float*)d_in[6];
    const float* bq_up    = (const float*)d_in[7];
    const float* wkv_down = (const float*)d_in[8];
    const float* bkv_down = (const float*)d_in[9];
    const float* gkv_ln   = (const float*)d_in[10];
    const float* bkv_ln   = (const float*)d_in[11];
    const float* wkv_up   = (const float*)d_in[12];
    const float* bkv_up   = (const float*)d_in[13];
    const float* w_out    = (const float*)d_in[14];
    const float* b_out    = (const float*)d_in[15];
    float* out = (float*)d_out;

    // Workspace layout (byte offsets, MB). Total 90 MB.
    //  0-16 : x_bf (dead after down-GEMM) / vt (written by up-GEMM V-epilogue)
    // 16-24 : lat fused [4096][1024] bf16 (dead after up-GEMMs)
    // 16-32 : attn_bf (written by flash; overlays lat + wd_t + wkvu_t, all dead)
    // 24-28 : wd_t fused [1024][2048]
    // 28-32 : wkvu_t   32-34 : wqu_t   34-42 : wout_t
    // 42-58 : q_bf     58-74 : k_bf [4096][2048] (compact K, V fused to vt)
    char* ws = (char*)d_ws;
    u16* x_bf    = (u16*)(ws);
    u16* vt      = (u16*)(ws);
    u16* lat     = (u16*)(ws + (16u << 20));
    u16* attn_bf = (u16*)(ws + (16u << 20));
    u16* wd_t    = (u16*)(ws + (24u << 20));
    u16* wkvu_t  = (u16*)(ws + (28u << 20));
    u16* wqu_t   = (u16*)(ws + (32u << 20));
    u16* wout_t  = (u16*)(ws + (34u << 20));
    u16* q_bf    = (u16*)(ws + (42u << 20));
    u16* k_bf    = (u16*)(ws + (58u << 20));

    const int M = B_ * S_;  // 4096
    dim3 blk(256);

    // prep: x cast + all 5 weight transposes in one launch
    prep_kernel<<<10496, blk, 0, stream>>>(
        wq_down, wkv_down, wq_up, wkv_up, w_out, x,
        wd_t, wqu_t, wkvu_t, wout_t, x_bf);

    // fused down-projection: [M,2048] @ [2048,1024] -> lat (q | kv), BN=64
    // (BN=64: 512 wgs = 2 blk/CU vs 1 at BN=128 -- R6 win)
    gemm_mfma_kernel<u16, 64><<<dim3((2 * L_) / 64, M / 128), blk, 0, stream>>>(
        x_bf, wd_t, bq_down, bkv_down, lat,
        M, 2 * L_, D_, D_, 2 * L_, L_);

    // fused LayerNorm over both halves
    layernorm_fused_kernel<<<2 * M, blk, 0, stream>>>(lat, gq_ln, bq_ln, gkv_ln, bkv_ln);

    // merged up-projections: kv-up (with fused V transpose) + q-up
    up_gemm_kernel<<<dim3(48, M / 128), blk, 0, stream>>>(
        lat, wkvu_t, wqu_t, bkv_up, bq_up, k_bf, vt, q_bf);

    // Flash attention v12 -> bf16 attn
    flash_attn_kernel<<<dim3((S_ / 64) * H_ * B_), blk, 0, stream>>>(
        q_bf, k_bf, vt, mask, attn_bf);

    // Output projection (fp32 out), BN=128 (512 wgs = 2 blk/CU -- R10 showed
    // BN=64's 4 blk/CU trades the MFMA:stage ratio at a net loss here)
    gemm_mfma_kernel<float, 128><<<dim3(D_ / 128, M / 128), blk, 0, stream>>>(
        attn_bf, wout_t, b_out, b_out, out,
        M, D_, D_, D_, D_, D_);
}

// Round 12
// 310.285 us; speedup vs baseline: 1.1128x; 1.0808x over previous
//
#include <hip/hip_runtime.h>
#include <math.h>
#include <type_traits>

typedef unsigned short u16;
typedef __attribute__((ext_vector_type(8))) short bf16x8;
typedef __attribute__((ext_vector_type(4))) float f32x4;

// Problem constants (fixed by the reference)
#define B_  2
#define S_  2048
#define D_  2048
#define H_  16
#define HD_ 128
#define L_  512
constexpr float EPS   = 1e-5f;
constexpr float SCALE = 0.08838834764831845f;           // 1/sqrt(128)

// Static-softmax score transform. R10 lesson: exp2f() is libm-precise (NOT
// v_exp_f32). Use the raw HW exp2 builtin when available (v_exp_f32 IS 2^x;
// exp2(-inf)=0 handles masked keys); else the v9 __expf path.
#if __has_builtin(__builtin_amdgcn_exp2f)
constexpr float SCORE_SCALE = 0.12751701840172524f;  // SCALE * log2(e)
constexpr float SCORE_SHIFT = -11.541560327111707f;  // -8 * log2(e)
__device__ __forceinline__ float expx(float x) { return __builtin_amdgcn_exp2f(x); }
#else
constexpr float SCORE_SCALE = 0.08838834764831845f;
constexpr float SCORE_SHIFT = -8.0f;
__device__ __forceinline__ float expx(float x) { return __expf(x); }
#endif

__device__ __forceinline__ u16 f2bf(float x) {
    unsigned u = __float_as_uint(x);
    u += 0x7fffu + ((u >> 16) & 1u);   // round-to-nearest-even
    return (u16)(u >> 16);
}
__device__ __forceinline__ float bf2f(u16 v) {
    return __uint_as_float(((unsigned)v) << 16);
}

// async global->LDS, 16 B per lane; LDS dest = lptr + lane*16 (wave-uniform base)
__device__ __forceinline__ void gl_lds16(const u16* g, u16* l) {
    __builtin_amdgcn_global_load_lds(
        (const __attribute__((address_space(1))) unsigned int*)g,
        (__attribute__((address_space(3))) unsigned int*)l, 16, 0, 0);
}

// ---------------------------------------------------------------------------
// bf16 MFMA GEMM (m97 structure, generic BK): C[M,N] = A[M,K]@Bt[N,K]^T+bias
// BM=128 x BN tile, 256 thr, 4 waves (2x2), per-wave 64 x BN/2.
// BK=64 (R12): halves K-iterations -> halves the per-step vmcnt(0)+barrier
// drains (the m97 structure's ~20% stall); MFMA:stage ratio unchanged; LDS
// 32KB (BN=128) keeps >=2 blk/CU (avoids m132's BK=128 occupancy cliff).
// BN rule (R6/R10 A-B): 1 blk/CU -> BN=64; else BN=128.
// Staging swizzle: write linear LDS from pre-swizzled global chunk
// c = sc ^ key(row); read chunk (h*4+g) ^ key(row). key = r&7 for BK=64
// ((r>>1)&3 for BK=32). LDS[row][p] = G[row][p^key] => read yields G[ra][ci].
// ---------------------------------------------------------------------------
template <int BK> __device__ __forceinline__ int swzkey(int r) {
    return (BK == 32) ? ((r >> 1) & 3) : (r & 7);
}

template <typename OutT, int BN, int BK>
__global__ __launch_bounds__(256)
void gemm_mfma_kernel(const u16* __restrict__ A, const u16* __restrict__ Bt,
                      const float* __restrict__ biasA,
                      const float* __restrict__ biasB, OutT* __restrict__ C,
                      int M, int N, int K, int lda, int ldc, int nsplit) {
    constexpr int NJ  = BN / 32;     // per-wave j-tiles
    constexpr int KH  = BK / 32;     // K fragments per row
    constexpr int CH  = BK / 8;      // 8-elem chunks per row
    constexpr int RPI = 64 / CH;     // rows staged per wave per issue
    __shared__ __align__(16) u16 As[128 * BK];
    __shared__ __align__(16) u16 Bs[BN * BK];

    const int tid  = threadIdx.x;
    const int wave = tid >> 6, lane = tid & 63;
    const int l15  = lane & 15, g = lane >> 4;
    const int wm   = wave >> 1, wn = wave & 1;
    const int m0   = blockIdx.y * 128, n0 = blockIdx.x * BN;

    const int sr = lane / CH;        // staging row within issue group
    const int sc = lane % CH;        // chunk slot

    f32x4 acc[4][NJ];
#pragma unroll
    for (int i = 0; i < 4; ++i)
#pragma unroll
        for (int j = 0; j < NJ; ++j) acc[i][j] = (f32x4)0.f;

    for (int k0 = 0; k0 < K; k0 += BK) {
#pragma unroll
        for (int t = 0; t < 128 / (4 * RPI); ++t) {   // A: 128 rows
            const int r = wave * 32 + t * RPI + sr;
            const int c = sc ^ swzkey<BK>(r);
            gl_lds16(A + (size_t)(m0 + r) * lda + k0 + c * 8,
                     &As[(wave * 32 + t * RPI) * BK]);
        }
#pragma unroll
        for (int t = 0; t < BN / (4 * RPI); ++t) {    // B: BN rows
            const int r = wave * (BN / 4) + t * RPI + sr;
            const int c = sc ^ swzkey<BK>(r);
            gl_lds16(Bt + (size_t)(n0 + r) * K + k0 + c * 8,
                     &Bs[(wave * (BN / 4) + t * RPI) * BK]);
        }
        __syncthreads();

        bf16x8 af[4][KH], bfr[NJ][KH];
#pragma unroll
        for (int i = 0; i < 4; ++i) {
            const int ra = wm * 64 + i * 16 + l15;
#pragma unroll
            for (int h = 0; h < KH; ++h)
                af[i][h] = *(const bf16x8*)
                    &As[ra * BK + ((h * 4 + g) ^ swzkey<BK>(ra)) * 8];
        }
#pragma unroll
        for (int j = 0; j < NJ; ++j) {
            const int rb = wn * (BN / 2) + j * 16 + l15;
#pragma unroll
            for (int h = 0; h < KH; ++h)
                bfr[j][h] = *(const bf16x8*)
                    &Bs[rb * BK + ((h * 4 + g) ^ swzkey<BK>(rb)) * 8];
        }
#pragma unroll
        for (int i = 0; i < 4; ++i)
#pragma unroll
            for (int j = 0; j < NJ; ++j)
#pragma unroll
                for (int h = 0; h < KH; ++h)
                    acc[i][j] = __builtin_amdgcn_mfma_f32_16x16x32_bf16(
                        af[i][h], bfr[j][h], acc[i][j], 0, 0, 0);
        __syncthreads();
    }

#pragma unroll
    for (int j = 0; j < NJ; ++j) {
        const int n  = n0 + wn * (BN / 2) + j * 16 + l15;
        const float bv = (n < nsplit) ? biasA[n] : biasB[n - nsplit];
#pragma unroll
        for (int i = 0; i < 4; ++i) {
            const int mb = m0 + wm * 64 + i * 16 + g * 4;
#pragma unroll
            for (int r = 0; r < 4; ++r) {
                float v = acc[i][j][r] + bv;
                if constexpr (std::is_same_v<OutT, float>)
                    C[(size_t)(mb + r) * ldc + n] = v;
                else
                    C[(size_t)(mb + r) * ldc + n] = f2bf(v);
            }
        }
    }
}

// ---------------------------------------------------------------------------
// Merged up-projection GEMM (kv-up + q-up in ONE launch), BK=64.
// Block-uniform dispatch on x: x<32 kv-up (K-half -> k_bf, V-half -> vt
// transposed); x>=32 q-up -> q_bf. Both read lat with lda = 2L, K=512.
// ---------------------------------------------------------------------------
__global__ __launch_bounds__(256)
void up_gemm_kernel(const u16* __restrict__ lat,
                    const u16* __restrict__ wkvu_t, const u16* __restrict__ wqu_t,
                    const float* __restrict__ bkv_up, const float* __restrict__ bq_up,
                    u16* __restrict__ k_bf, u16* __restrict__ vt,
                    u16* __restrict__ q_bf) {
    constexpr int BK = 64;
    __shared__ __align__(16) u16 As[128 * BK];
    __shared__ __align__(16) u16 Bs[128 * BK];

    const int bx    = blockIdx.x;
    const bool iskv = bx < 32;
    const u16* A    = iskv ? lat + L_ : lat;
    const u16* Bt   = iskv ? wkvu_t : wqu_t;
    const float* bias = iskv ? bkv_up : bq_up;
    const int n0    = (iskv ? bx : bx - 32) * 128;
    const int m0    = blockIdx.y * 128;
    constexpr int K = L_, lda = 2 * L_;

    const int tid  = threadIdx.x;
    const int wave = tid >> 6, lane = tid & 63;
    const int l15  = lane & 15, g = lane >> 4;
    const int wm   = wave >> 1, wn = wave & 1;

    const int sr = lane >> 3;        // 8 chunks/row
    const int sc = lane & 7;

    f32x4 acc[4][4];
#pragma unroll
    for (int i = 0; i < 4; ++i)
#pragma unroll
        for (int j = 0; j < 4; ++j) acc[i][j] = (f32x4)0.f;

    for (int k0 = 0; k0 < K; k0 += BK) {
#pragma unroll
        for (int t = 0; t < 4; ++t) {
            const int r = wave * 32 + t * 8 + sr;
            const int c = sc ^ (r & 7);
            gl_lds16(A  + (size_t)(m0 + r) * lda + k0 + c * 8,
                     &As[(wave * 32 + t * 8) * BK]);
            gl_lds16(Bt + (size_t)(n0 + r) * K + k0 + c * 8,
                     &Bs[(wave * 32 + t * 8) * BK]);
        }
        __syncthreads();

        bf16x8 af[4][2], bfr[4][2];
#pragma unroll
        for (int i = 0; i < 4; ++i) {
            const int ra = wm * 64 + i * 16 + l15;
            const int rb = wn * 64 + i * 16 + l15;
#pragma unroll
            for (int h = 0; h < 2; ++h) {
                af[i][h]  = *(const bf16x8*)
                    &As[ra * BK + ((h * 4 + g) ^ (ra & 7)) * 8];
                bfr[i][h] = *(const bf16x8*)
                    &Bs[rb * BK + ((h * 4 + g) ^ (rb & 7)) * 8];
            }
        }
#pragma unroll
        for (int i = 0; i < 4; ++i)
#pragma unroll
            for (int j = 0; j < 4; ++j)
#pragma unroll
                for (int h = 0; h < 2; ++h)
                    acc[i][j] = __builtin_amdgcn_mfma_f32_16x16x32_bf16(
                        af[i][h], bfr[j][h], acc[i][j], 0, 0, 0);
        __syncthreads();
    }

    const bool vstore = iskv && (n0 >= D_);   // block-uniform
#pragma unroll
    for (int j = 0; j < 4; ++j) {
        const int n  = n0 + wn * 64 + j * 16 + l15;
        const float bv = bias[n];
        if (vstore) {
            // transposed V store: vt[(b*H+h)*HD+d][s], s = m (4 consecutive)
            const int dg = n - D_;
            const int hh = dg >> 7, dd = dg & 127;
            u16* vrow = vt + ((size_t)(((m0 >> 11) * H_ + hh) * HD_ + dd)) * S_;
#pragma unroll
            for (int i = 0; i < 4; ++i) {
                const int mb = m0 + wm * 64 + i * 16 + g * 4;
                ushort4 o;
                o.x = f2bf(acc[i][j][0] + bv);
                o.y = f2bf(acc[i][j][1] + bv);
                o.z = f2bf(acc[i][j][2] + bv);
                o.w = f2bf(acc[i][j][3] + bv);
                *(ushort4*)&vrow[mb & (S_ - 1)] = o;
            }
        } else {
            u16* C = iskv ? k_bf : q_bf;
#pragma unroll
            for (int i = 0; i < 4; ++i) {
                const int mb = m0 + wm * 64 + i * 16 + g * 4;
#pragma unroll
                for (int r = 0; r < 4; ++r)
                    C[(size_t)(mb + r) * D_ + n] = f2bf(acc[i][j][r] + bv);
            }
        }
    }
}

// ---------------------------------------------------------------------------
// Prep: all 5 weight transposes + x fp32->bf16 cast in ONE launch.
// ---------------------------------------------------------------------------
__global__ __launch_bounds__(256)
void prep_kernel(const float* __restrict__ wqd,  const float* __restrict__ wkvd,
                 const float* __restrict__ wqu,  const float* __restrict__ wkvu,
                 const float* __restrict__ wo,   const float* __restrict__ x,
                 u16* __restrict__ wd_t,  u16* __restrict__ wqu_t,
                 u16* __restrict__ wkvu_t, u16* __restrict__ wout_t,
                 u16* __restrict__ x_bf) {
    int bid = blockIdx.x;
    if (bid >= 2304) {   // x cast: 8192 blocks x 256 thr x float4
        const int i = (bid - 2304) * 256 + threadIdx.x;
        float4 f = ((const float4*)x)[i];
        ushort4 o;
        o.x = f2bf(f.x); o.y = f2bf(f.y); o.z = f2bf(f.z); o.w = f2bf(f.w);
        ((ushort4*)x_bf)[i] = o;
        return;
    }
    const float* W; u16* Wt; int K, N;
    if (bid < 256)       { W = wqd;  Wt = wd_t;                      K = 2048; N = 512; }
    else if (bid < 512)  { W = wkvd; Wt = wd_t + (size_t)512 * 2048; K = 2048; N = 512;  bid -= 256; }
    else if (bid < 768)  { W = wqu;  Wt = wqu_t;                     K = 512;  N = 2048; bid -= 512; }
    else if (bid < 1280) { W = wkvu; Wt = wkvu_t;                    K = 512;  N = 4096; bid -= 768; }
    else                 { W = wo;   Wt = wout_t;                    K = 2048; N = 2048; bid -= 1280; }
    const int nblk = N / 64;
    const int n0 = (bid % nblk) * 64, k0 = (bid / nblk) * 64;

    __shared__ u16 T[64][72];
    const int t = threadIdx.x;
    {
        const int kr = t >> 2, nc = (t & 3) * 16;
#pragma unroll
        for (int v = 0; v < 4; ++v) {
            float4 f = *(const float4*)&W[(size_t)(k0 + kr) * N + n0 + nc + v * 4];
            T[nc + v * 4 + 0][kr] = f2bf(f.x);
            T[nc + v * 4 + 1][kr] = f2bf(f.y);
            T[nc + v * 4 + 2][kr] = f2bf(f.z);
            T[nc + v * 4 + 3][kr] = f2bf(f.w);
        }
    }
    __syncthreads();
    {
        const int nr = t >> 2, kc = (t & 3) * 16;
        union { u16 u[16]; uint4 q[2]; } o;
#pragma unroll
        for (int i = 0; i < 16; ++i) o.u[i] = T[nr][kc + i];
        uint4* dst = (uint4*)&Wt[(size_t)(n0 + nr) * K + k0 + kc];
        dst[0] = o.q[0]; dst[1] = o.q[1];
    }
}

// ---------------------------------------------------------------------------
// In-place bf16 row LayerNorm over the fused latent [M][1024].
// ---------------------------------------------------------------------------
__global__ __launch_bounds__(256)
void layernorm_fused_kernel(u16* __restrict__ buf,
                            const float* __restrict__ gq,
                            const float* __restrict__ bq,
                            const float* __restrict__ gkv,
                            const float* __restrict__ bkv) {
    const int r    = blockIdx.x;
    const int half = r & 1;
    u16* p = buf + (size_t)(r >> 1) * 1024 + half * 512;
    const float* g    = half ? gkv : gq;
    const float* bvec = half ? bkv : bq;
    const int tid = threadIdx.x;

    float x0 = bf2f(p[tid]), x1 = bf2f(p[tid + 256]);
    float s  = x0 + x1;
    float sq = x0 * x0 + x1 * x1;

    __shared__ float red[8];
    __shared__ float stats[2];

#pragma unroll
    for (int off = 32; off; off >>= 1) {
        s  += __shfl_down(s, off);
        sq += __shfl_down(sq, off);
    }
    const int wave = tid >> 6;
    if ((tid & 63) == 0) { red[wave] = s; red[wave + 4] = sq; }
    __syncthreads();
    if (tid == 0) {
        float ts = red[0] + red[1] + red[2] + red[3];
        float tq = red[4] + red[5] + red[6] + red[7];
        float mean = ts / (float)L_;
        float var  = tq / (float)L_ - mean * mean;
        stats[0] = mean;
        stats[1] = rsqrtf(var + EPS);
    }
    __syncthreads();
    const float mean = stats[0], rstd = stats[1];
    p[tid]       = f2bf((x0 - mean) * rstd * g[tid]       + bvec[tid]);
    p[tid + 256] = f2bf((x1 - mean) * rstd * g[tid + 256] + bvec[tid + 256]);
}

// ---------------------------------------------------------------------------
// Flash attention v12 (UNCHANGED from R11 -- anchor: ~73us, MfmaUtil ~21,
// VALUBusy ~33). v9 structure + expx() static softmax.
// LDS: 32KB Kdbuf + 32KB Vdbuf + 9KB Pl = 73KB -> 2 blocks/CU.
// ---------------------------------------------------------------------------
#define PPITCH 72

__global__ __launch_bounds__(256)
void flash_attn_kernel(const u16* __restrict__ qbf, const u16* __restrict__ kbf,
                       const u16* __restrict__ vt,
                       const unsigned char* __restrict__ mask,
                       u16* __restrict__ out) {
    const int x    = blockIdx.x;
    const int qgrp = (S_ / 64 - 1) - (x >> 5);   // heavy blocks first
    const int hb   = x & 31;
    const int h    = hb >> 1, b = hb & 1;
    const int tid  = threadIdx.x;
    const int wave = tid >> 6, lane = tid & 63;
    const int l15  = lane & 15, g = lane >> 4;
    const int q0   = qgrp * 64 + wave * 16;      // this wave's 16 queries

    __shared__ __align__(16) u16 Ks[2][64][128];   // 2 x 16 KB, key x d
    __shared__ __align__(16) u16 Vs[2][128][64];   // 2 x 16 KB, d x key
    __shared__ __align__(16) u16 Pl[4][16][PPITCH];

    const u16* kbase = kbf + (size_t)b * S_ * D_ + h * HD_;
    const u16* vbase = vt + (size_t)((b * H_ + h) * HD_) * S_;
    const unsigned char* mbase = mask + b * S_;

    const int kr_l = lane >> 4;          // K: row within 4-row chunk
    const int kb_l = (lane & 15) * 16;   // K: byte within 256B row
    const int vr_l = lane >> 3;          // V: row within 8-row chunk
    const int vb_l = (lane & 7) * 16;    // V: byte within 128B row

    auto STAGE = [&](int bi, int k0s) {
#pragma unroll
        for (int j = 0; j < 4; ++j) {
            const int rr = wave * 16 + j * 4 + kr_l;          // key row 0..63
            gl_lds16(kbase + (size_t)(k0s + rr) * D_ +
                         ((kb_l ^ ((rr & 7) << 4)) >> 1),
                     &Ks[bi][wave * 16 + j * 4][0]);
            const int rv = wave * 32 + j * 8 + vr_l;          // d row 0..127
            gl_lds16(vbase + (size_t)rv * S_ + k0s +
                         ((vb_l ^ ((rv & 7) << 4)) >> 1),
                     &Vs[bi][wave * 32 + j * 8][0]);
        }
    };

    // Q fragments (A-operand): row l15, k = c*32 + g*8 + j
    bf16x8 qf[4];
#pragma unroll
    for (int c = 0; c < 4; ++c)
        qf[c] = *(const bf16x8*)(qbf +
            (size_t)(b * S_ + q0 + l15) * D_ + h * HD_ + c * 32 + g * 8);

    // all-ones bf16 B-fragment for the row-sum MFMA
    bf16x8 ones;
#pragma unroll
    for (int j = 0; j < 8; ++j) ones[j] = (short)0x3f80;  // 1.0f in bf16

    f32x4 o[8];
#pragma unroll
    for (int i = 0; i < 8; ++i) o[i] = (f32x4)0.f;
    f32x4 osum = (f32x4)0.f;

    const int qb  = q0 + 4 * g;
    const int ksw = (l15 & 7) << 4;        // read-side XOR key (bytes)
    const int nt  = qgrp + 1;              // uniform across the block

    STAGE(0, 0);
    __syncthreads();   // implicit vmcnt(0) drain before s_barrier

    for (int kt = 0; kt < nt; ++kt) {
        const int k0  = kt * 64;
        const int cur = kt & 1;
        if (kt + 1 < nt) STAGE(cur ^ 1, k0 + 64);   // prefetch next tile

        // padding mask -> additive bias (static shift, or -inf)
        float nb[4];
#pragma unroll
        for (int cc = 0; cc < 4; ++cc)
            nb[cc] = mbase[k0 + cc * 16 + l15] ? -INFINITY : SCORE_SHIFT;

        // QK^T from LDS: 4 independent accumulation chains of 4 MFMAs
        f32x4 s[4];
#pragma unroll
        for (int cc = 0; cc < 4; ++cc) {
            bf16x8 kf[4];
#pragma unroll
            for (int c = 0; c < 4; ++c)
                kf[c] = *(const bf16x8*)&Ks[cur][cc * 16 + l15]
                    [((c * 64 + g * 16) ^ ksw) >> 1];
            f32x4 t = (f32x4)0.f;
#pragma unroll
            for (int c = 0; c < 4; ++c)
                t = __builtin_amdgcn_mfma_f32_16x16x32_bf16(qf[c], kf[c], t, 0, 0, 0);
            s[cc] = t;
        }

        // scale + shift/padding in one FMA per score
#pragma unroll
        for (int cc = 0; cc < 4; ++cc)
#pragma unroll
            for (int r = 0; r < 4; ++r)
                s[cc][r] = fmaf(s[cc][r], SCORE_SCALE, nb[cc]);

        // causal mask: only the final tile contains keys > query
        if (kt == nt - 1) {
#pragma unroll
            for (int cc = 0; cc < 4; ++cc) {
                const int kk = k0 + cc * 16 + l15;
#pragma unroll
                for (int r = 0; r < 4; ++r)
                    if (kk > qb + r) s[cc][r] = -INFINITY;
            }
        }

        // P = expx(s): C-layout -> LDS -> A-layout (no max, no rescale)
#pragma unroll
        for (int cc = 0; cc < 4; ++cc)
#pragma unroll
            for (int r = 0; r < 4; ++r)
                Pl[wave][4 * g + r][cc * 16 + l15] = f2bf(expx(s[cc][r]));

        const bf16x8 pf0 = *(const bf16x8*)&Pl[wave][l15][g * 8];
        const bf16x8 pf1 = *(const bf16x8*)&Pl[wave][l15][32 + g * 8];

        // PV from LDS over 64 keys + ones-column row-sum accumulation
#pragma unroll
        for (int i = 0; i < 8; ++i) {
            bf16x8 vf0 = *(const bf16x8*)&Vs[cur][16 * i + l15]
                [((g * 16) ^ ksw) >> 1];
            bf16x8 vf1 = *(const bf16x8*)&Vs[cur][16 * i + l15]
                [((g * 16 + 64) ^ ksw) >> 1];
            o[i] = __builtin_amdgcn_mfma_f32_16x16x32_bf16(pf0, vf0, o[i], 0, 0, 0);
            o[i] = __builtin_amdgcn_mfma_f32_16x16x32_bf16(pf1, vf1, o[i], 0, 0, 0);
        }
        osum = __builtin_amdgcn_mfma_f32_16x16x32_bf16(pf0, ones, osum, 0, 0, 0);
        osum = __builtin_amdgcn_mfma_f32_16x16x32_bf16(pf1, ones, osum, 0, 0, 0);

        __syncthreads();   // drains prefetch (vmcnt(0)) + WAR on buf[cur]
    }

    // epilogue: normalize by osum (row-sum of bf16 P, same rows as o) + store
    float inv[4];
#pragma unroll
    for (int r = 0; r < 4; ++r) inv[r] = 1.0f / osum[r];
#pragma unroll
    for (int i = 0; i < 8; ++i)
#pragma unroll
        for (int r = 0; r < 4; ++r)
            out[(size_t)(b * S_ + q0 + 4 * g + r) * D_ +
                h * HD_ + 16 * i + l15] = f2bf(o[i][r] * inv[r]);
}

// ---------------------------------------------------------------------------
extern "C" void kernel_launch(void* const* d_in, const int* in_sizes, int n_in,
                              void* d_out, int out_size, void* d_ws, size_t ws_size,
                              hipStream_t stream) {
    const float* x        = (const float*)d_in[0];
    const unsigned char* mask = (const unsigned char*)d_in[1];
    const float* wq_down  = (const float*)d_in[2];
    const float* bq_down  = (const float*)d_in[3];
    const float* gq_ln    = (const float*)d_in[4];
    const float* bq_ln    = (const float*)d_in[5];
    const float* wq_up    = (const float*)d_in[6];
    const float* bq_up    = (const float*)d_in[7];
    const float* wkv_down = (const float*)d_in[8];
    const float* bkv_down = (const float*)d_in[9];
    const float* gkv_ln   = (const float*)d_in[10];
    const float* bkv_ln   = (const float*)d_in[11];
    const float* wkv_up   = (const float*)d_in[12];
    const float* bkv_up   = (const float*)d_in[13];
    const float* w_out    = (const float*)d_in[14];
    const float* b_out    = (const float*)d_in[15];
    float* out = (float*)d_out;

    // Workspace layout (byte offsets, MB). Total 90 MB.
    //  0-16 : x_bf (dead after down-GEMM) / vt (written by up-GEMM V-epilogue)
    // 16-24 : lat fused [4096][1024] bf16 (dead after up-GEMMs)
    // 16-32 : attn_bf (written by flash; overlays lat + wd_t + wkvu_t, all dead)
    // 24-28 : wd_t fused [1024][2048]
    // 28-32 : wkvu_t   32-34 : wqu_t   34-42 : wout_t
    // 42-58 : q_bf     58-74 : k_bf [4096][2048] (compact K, V fused to vt)
    char* ws = (char*)d_ws;
    u16* x_bf    = (u16*)(ws);
    u16* vt      = (u16*)(ws);
    u16* lat     = (u16*)(ws + (16u << 20));
    u16* attn_bf = (u16*)(ws + (16u << 20));
    u16* wd_t    = (u16*)(ws + (24u << 20));
    u16* wkvu_t  = (u16*)(ws + (28u << 20));
    u16* wqu_t   = (u16*)(ws + (32u << 20));
    u16* wout_t  = (u16*)(ws + (34u << 20));
    u16* q_bf    = (u16*)(ws + (42u << 20));
    u16* k_bf    = (u16*)(ws + (58u << 20));

    const int M = B_ * S_;  // 4096
    dim3 blk(256);

    // prep: x cast + all 5 weight transposes in one launch
    prep_kernel<<<10496, blk, 0, stream>>>(
        wq_down, wkv_down, wq_up, wkv_up, w_out, x,
        wd_t, wqu_t, wkvu_t, wout_t, x_bf);

    // fused down-projection: [M,2048] @ [2048,1024] -> lat (q | kv),
    // BN=64 (2 blk/CU, R6 win) + BK=64 (half the barrier drains)
    gemm_mfma_kernel<u16, 64, 64><<<dim3((2 * L_) / 64, M / 128), blk, 0, stream>>>(
        x_bf, wd_t, bq_down, bkv_down, lat,
        M, 2 * L_, D_, D_, 2 * L_, L_);

    // fused LayerNorm over both halves
    layernorm_fused_kernel<<<2 * M, blk, 0, stream>>>(lat, gq_ln, bq_ln, gkv_ln, bkv_ln);

    // merged up-projections: kv-up (with fused V transpose) + q-up, BK=64
    up_gemm_kernel<<<dim3(48, M / 128), blk, 0, stream>>>(
        lat, wkvu_t, wqu_t, bkv_up, bq_up, k_bf, vt, q_bf);

    // Flash attention v12 -> bf16 attn (unchanged anchor)
    flash_attn_kernel<<<dim3((S_ / 64) * H_ * B_), blk, 0, stream>>>(
        q_bf, k_bf, vt, mask, attn_bf);

    // Output projection (fp32 out), BN=128 (2 blk/CU sweet spot) + BK=64
    gemm_mfma_kernel<float, 128, 64><<<dim3(D_ / 128, M / 128), blk, 0, stream>>>(
        attn_bf, wout_t, b_out, b_out, out,
        M, D_, D_, D_, D_, D_);
}

// Round 13
// 309.386 us; speedup vs baseline: 1.1160x; 1.0029x over previous
//
#include <hip/hip_runtime.h>
#include <math.h>
#include <type_traits>

typedef unsigned short u16;
typedef __attribute__((ext_vector_type(8))) short bf16x8;
typedef __attribute__((ext_vector_type(4))) float f32x4;

// Problem constants (fixed by the reference)
#define B_  2
#define S_  2048
#define D_  2048
#define H_  16
#define HD_ 128
#define L_  512
constexpr float EPS   = 1e-5f;
constexpr float SCALE = 0.08838834764831845f;           // 1/sqrt(128)

// Static-softmax score transform. R10 lesson: exp2f() is libm-precise (NOT
// v_exp_f32). Use the raw HW exp2 builtin when available (v_exp_f32 IS 2^x;
// exp2(-inf)=0 handles masked keys); else the v9 __expf path.
#if __has_builtin(__builtin_amdgcn_exp2f)
constexpr float SCORE_SCALE = 0.12751701840172524f;  // SCALE * log2(e)
constexpr float SCORE_SHIFT = -11.541560327111707f;  // -8 * log2(e)
__device__ __forceinline__ float expx(float x) { return __builtin_amdgcn_exp2f(x); }
#else
constexpr float SCORE_SCALE = 0.08838834764831845f;
constexpr float SCORE_SHIFT = -8.0f;
__device__ __forceinline__ float expx(float x) { return __expf(x); }
#endif

__device__ __forceinline__ u16 f2bf(float x) {
    unsigned u = __float_as_uint(x);
    u += 0x7fffu + ((u >> 16) & 1u);   // round-to-nearest-even
    return (u16)(u >> 16);
}
__device__ __forceinline__ float bf2f(u16 v) {
    return __uint_as_float(((unsigned)v) << 16);
}

// async global->LDS, 16 B per lane; LDS dest = lptr + lane*16 (wave-uniform base)
__device__ __forceinline__ void gl_lds16(const u16* g, u16* l) {
    __builtin_amdgcn_global_load_lds(
        (const __attribute__((address_space(1))) unsigned int*)g,
        (__attribute__((address_space(3))) unsigned int*)l, 16, 0, 0);
}

// ---------------------------------------------------------------------------
// bf16 MFMA GEMM (m97 structure, generic BK): C[M,N] = A[M,K]@Bt[N,K]^T+bias
// BM=128 x BN tile, 256 thr, 4 waves (2x2), per-wave 64 x BN/2.
// BK selection (R12/R13): the per-K-step vmcnt(0)+barrier drain is the
// structure's dominant fixed cost; raise BK as far as RESIDENCY allows:
//   out  (grid 512 = 2 blk/CU grid-capped): BK=128, LDS 64KB, capacity 2. OK.
//   down (BN=64, grid 512 = 2 blk/CU):      BK=128, LDS 48KB, capacity 3. OK.
//   up   (grid 1536, wants ~6/CU):          BK=64 (32KB, capacity 5) -- BK=128
//         would cut residency 5->2 = m132's trap. NOT raised.
// Compute loop is PER-H (one 32-wide K-slice of fragments live at a time) so
// register pressure is BK-independent (~32 VGPR fragments live).
// BN rule (R6/R10 A-B): 1 blk/CU -> BN=64; else BN=128.
// Staging swizzle: write linear LDS from pre-swizzled global chunk
// c = sc ^ (r&7); read chunk (h*4+g) ^ (ra&7). 3-bit key XOR is a per-row
// bijection on chunk slots; 16 lanes -> 8 slots x 2-way = free (m136).
// ---------------------------------------------------------------------------
template <int BK> __device__ __forceinline__ int swzkey(int r) {
    return (BK == 32) ? ((r >> 1) & 3) : (r & 7);
}

template <typename OutT, int BN, int BK>
__global__ __launch_bounds__(256)
void gemm_mfma_kernel(const u16* __restrict__ A, const u16* __restrict__ Bt,
                      const float* __restrict__ biasA,
                      const float* __restrict__ biasB, OutT* __restrict__ C,
                      int M, int N, int K, int lda, int ldc, int nsplit) {
    constexpr int NJ  = BN / 32;     // per-wave j-tiles
    constexpr int KH  = BK / 32;     // 32-wide K-slices per step
    constexpr int CH  = BK / 8;      // 8-elem chunks per row
    constexpr int RPI = 64 / CH;     // rows staged per wave per issue
    __shared__ __align__(16) u16 As[128 * BK];
    __shared__ __align__(16) u16 Bs[BN * BK];

    const int tid  = threadIdx.x;
    const int wave = tid >> 6, lane = tid & 63;
    const int l15  = lane & 15, g = lane >> 4;
    const int wm   = wave >> 1, wn = wave & 1;
    const int m0   = blockIdx.y * 128, n0 = blockIdx.x * BN;

    const int sr = lane / CH;        // staging row within issue group
    const int sc = lane % CH;        // chunk slot

    f32x4 acc[4][NJ];
#pragma unroll
    for (int i = 0; i < 4; ++i)
#pragma unroll
        for (int j = 0; j < NJ; ++j) acc[i][j] = (f32x4)0.f;

    for (int k0 = 0; k0 < K; k0 += BK) {
#pragma unroll
        for (int t = 0; t < 128 / (4 * RPI); ++t) {   // A: 128 rows
            const int r = wave * 32 + t * RPI + sr;
            const int c = sc ^ swzkey<BK>(r);
            gl_lds16(A + (size_t)(m0 + r) * lda + k0 + c * 8,
                     &As[(wave * 32 + t * RPI) * BK]);
        }
#pragma unroll
        for (int t = 0; t < BN / (4 * RPI); ++t) {    // B: BN rows
            const int r = wave * (BN / 4) + t * RPI + sr;
            const int c = sc ^ swzkey<BK>(r);
            gl_lds16(Bt + (size_t)(n0 + r) * K + k0 + c * 8,
                     &Bs[(wave * (BN / 4) + t * RPI) * BK]);
        }
        __syncthreads();

#pragma unroll
        for (int h = 0; h < KH; ++h) {
            bf16x8 af[4], bfr[NJ];
#pragma unroll
            for (int i = 0; i < 4; ++i) {
                const int ra = wm * 64 + i * 16 + l15;
                af[i] = *(const bf16x8*)
                    &As[ra * BK + ((h * 4 + g) ^ swzkey<BK>(ra)) * 8];
            }
#pragma unroll
            for (int j = 0; j < NJ; ++j) {
                const int rb = wn * (BN / 2) + j * 16 + l15;
                bfr[j] = *(const bf16x8*)
                    &Bs[rb * BK + ((h * 4 + g) ^ swzkey<BK>(rb)) * 8];
            }
#pragma unroll
            for (int i = 0; i < 4; ++i)
#pragma unroll
                for (int j = 0; j < NJ; ++j)
                    acc[i][j] = __builtin_amdgcn_mfma_f32_16x16x32_bf16(
                        af[i], bfr[j], acc[i][j], 0, 0, 0);
        }
        __syncthreads();
    }

#pragma unroll
    for (int j = 0; j < NJ; ++j) {
        const int n  = n0 + wn * (BN / 2) + j * 16 + l15;
        const float bv = (n < nsplit) ? biasA[n] : biasB[n - nsplit];
#pragma unroll
        for (int i = 0; i < 4; ++i) {
            const int mb = m0 + wm * 64 + i * 16 + g * 4;
#pragma unroll
            for (int r = 0; r < 4; ++r) {
                float v = acc[i][j][r] + bv;
                if constexpr (std::is_same_v<OutT, float>)
                    C[(size_t)(mb + r) * ldc + n] = v;
                else
                    C[(size_t)(mb + r) * ldc + n] = f2bf(v);
            }
        }
    }
}

// ---------------------------------------------------------------------------
// Merged up-projection GEMM (kv-up + q-up in ONE launch), BK=64 (residency 5
// blocks/CU at 32KB LDS -- NOT raised to BK=128, see header).
// Block-uniform dispatch on x: x<32 kv-up (K-half -> k_bf, V-half -> vt
// transposed); x>=32 q-up -> q_bf. Both read lat with lda = 2L, K=512.
// ---------------------------------------------------------------------------
__global__ __launch_bounds__(256)
void up_gemm_kernel(const u16* __restrict__ lat,
                    const u16* __restrict__ wkvu_t, const u16* __restrict__ wqu_t,
                    const float* __restrict__ bkv_up, const float* __restrict__ bq_up,
                    u16* __restrict__ k_bf, u16* __restrict__ vt,
                    u16* __restrict__ q_bf) {
    constexpr int BK = 64;
    __shared__ __align__(16) u16 As[128 * BK];
    __shared__ __align__(16) u16 Bs[128 * BK];

    const int bx    = blockIdx.x;
    const bool iskv = bx < 32;
    const u16* A    = iskv ? lat + L_ : lat;
    const u16* Bt   = iskv ? wkvu_t : wqu_t;
    const float* bias = iskv ? bkv_up : bq_up;
    const int n0    = (iskv ? bx : bx - 32) * 128;
    const int m0    = blockIdx.y * 128;
    constexpr int K = L_, lda = 2 * L_;

    const int tid  = threadIdx.x;
    const int wave = tid >> 6, lane = tid & 63;
    const int l15  = lane & 15, g = lane >> 4;
    const int wm   = wave >> 1, wn = wave & 1;

    const int sr = lane >> 3;        // 8 chunks/row
    const int sc = lane & 7;

    f32x4 acc[4][4];
#pragma unroll
    for (int i = 0; i < 4; ++i)
#pragma unroll
        for (int j = 0; j < 4; ++j) acc[i][j] = (f32x4)0.f;

    for (int k0 = 0; k0 < K; k0 += BK) {
#pragma unroll
        for (int t = 0; t < 4; ++t) {
            const int r = wave * 32 + t * 8 + sr;
            const int c = sc ^ (r & 7);
            gl_lds16(A  + (size_t)(m0 + r) * lda + k0 + c * 8,
                     &As[(wave * 32 + t * 8) * BK]);
            gl_lds16(Bt + (size_t)(n0 + r) * K + k0 + c * 8,
                     &Bs[(wave * 32 + t * 8) * BK]);
        }
        __syncthreads();

#pragma unroll
        for (int h = 0; h < 2; ++h) {
            bf16x8 af[4], bfr[4];
#pragma unroll
            for (int i = 0; i < 4; ++i) {
                const int ra = wm * 64 + i * 16 + l15;
                const int rb = wn * 64 + i * 16 + l15;
                af[i]  = *(const bf16x8*)
                    &As[ra * BK + ((h * 4 + g) ^ (ra & 7)) * 8];
                bfr[i] = *(const bf16x8*)
                    &Bs[rb * BK + ((h * 4 + g) ^ (rb & 7)) * 8];
            }
#pragma unroll
            for (int i = 0; i < 4; ++i)
#pragma unroll
                for (int j = 0; j < 4; ++j)
                    acc[i][j] = __builtin_amdgcn_mfma_f32_16x16x32_bf16(
                        af[i], bfr[j], acc[i][j], 0, 0, 0);
        }
        __syncthreads();
    }

    const bool vstore = iskv && (n0 >= D_);   // block-uniform
#pragma unroll
    for (int j = 0; j < 4; ++j) {
        const int n  = n0 + wn * 64 + j * 16 + l15;
        const float bv = bias[n];
        if (vstore) {
            // transposed V store: vt[(b*H+h)*HD+d][s], s = m (4 consecutive)
            const int dg = n - D_;
            const int hh = dg >> 7, dd = dg & 127;
            u16* vrow = vt + ((size_t)(((m0 >> 11) * H_ + hh) * HD_ + dd)) * S_;
#pragma unroll
            for (int i = 0; i < 4; ++i) {
                const int mb = m0 + wm * 64 + i * 16 + g * 4;
                ushort4 o;
                o.x = f2bf(acc[i][j][0] + bv);
                o.y = f2bf(acc[i][j][1] + bv);
                o.z = f2bf(acc[i][j][2] + bv);
                o.w = f2bf(acc[i][j][3] + bv);
                *(ushort4*)&vrow[mb & (S_ - 1)] = o;
            }
        } else {
            u16* C = iskv ? k_bf : q_bf;
#pragma unroll
            for (int i = 0; i < 4; ++i) {
                const int mb = m0 + wm * 64 + i * 16 + g * 4;
#pragma unroll
                for (int r = 0; r < 4; ++r)
                    C[(size_t)(mb + r) * D_ + n] = f2bf(acc[i][j][r] + bv);
            }
        }
    }
}

// ---------------------------------------------------------------------------
// Prep: all 5 weight transposes + x fp32->bf16 cast in ONE launch.
// ---------------------------------------------------------------------------
__global__ __launch_bounds__(256)
void prep_kernel(const float* __restrict__ wqd,  const float* __restrict__ wkvd,
                 const float* __restrict__ wqu,  const float* __restrict__ wkvu,
                 const float* __restrict__ wo,   const float* __restrict__ x,
                 u16* __restrict__ wd_t,  u16* __restrict__ wqu_t,
                 u16* __restrict__ wkvu_t, u16* __restrict__ wout_t,
                 u16* __restrict__ x_bf) {
    int bid = blockIdx.x;
    if (bid >= 2304) {   // x cast: 8192 blocks x 256 thr x float4
        const int i = (bid - 2304) * 256 + threadIdx.x;
        float4 f = ((const float4*)x)[i];
        ushort4 o;
        o.x = f2bf(f.x); o.y = f2bf(f.y); o.z = f2bf(f.z); o.w = f2bf(f.w);
        ((ushort4*)x_bf)[i] = o;
        return;
    }
    const float* W; u16* Wt; int K, N;
    if (bid < 256)       { W = wqd;  Wt = wd_t;                      K = 2048; N = 512; }
    else if (bid < 512)  { W = wkvd; Wt = wd_t + (size_t)512 * 2048; K = 2048; N = 512;  bid -= 256; }
    else if (bid < 768)  { W = wqu;  Wt = wqu_t;                     K = 512;  N = 2048; bid -= 512; }
    else if (bid < 1280) { W = wkvu; Wt = wkvu_t;                    K = 512;  N = 4096; bid -= 768; }
    else                 { W = wo;   Wt = wout_t;                    K = 2048; N = 2048; bid -= 1280; }
    const int nblk = N / 64;
    const int n0 = (bid % nblk) * 64, k0 = (bid / nblk) * 64;

    __shared__ u16 T[64][72];
    const int t = threadIdx.x;
    {
        const int kr = t >> 2, nc = (t & 3) * 16;
#pragma unroll
        for (int v = 0; v < 4; ++v) {
            float4 f = *(const float4*)&W[(size_t)(k0 + kr) * N + n0 + nc + v * 4];
            T[nc + v * 4 + 0][kr] = f2bf(f.x);
            T[nc + v * 4 + 1][kr] = f2bf(f.y);
            T[nc + v * 4 + 2][kr] = f2bf(f.z);
            T[nc + v * 4 + 3][kr] = f2bf(f.w);
        }
    }
    __syncthreads();
    {
        const int nr = t >> 2, kc = (t & 3) * 16;
        union { u16 u[16]; uint4 q[2]; } o;
#pragma unroll
        for (int i = 0; i < 16; ++i) o.u[i] = T[nr][kc + i];
        uint4* dst = (uint4*)&Wt[(size_t)(n0 + nr) * K + k0 + kc];
        dst[0] = o.q[0]; dst[1] = o.q[1];
    }
}

// ---------------------------------------------------------------------------
// In-place bf16 row LayerNorm over the fused latent [M][1024].
// ---------------------------------------------------------------------------
__global__ __launch_bounds__(256)
void layernorm_fused_kernel(u16* __restrict__ buf,
                            const float* __restrict__ gq,
                            const float* __restrict__ bq,
                            const float* __restrict__ gkv,
                            const float* __restrict__ bkv) {
    const int r    = blockIdx.x;
    const int half = r & 1;
    u16* p = buf + (size_t)(r >> 1) * 1024 + half * 512;
    const float* g    = half ? gkv : gq;
    const float* bvec = half ? bkv : bq;
    const int tid = threadIdx.x;

    float x0 = bf2f(p[tid]), x1 = bf2f(p[tid + 256]);
    float s  = x0 + x1;
    float sq = x0 * x0 + x1 * x1;

    __shared__ float red[8];
    __shared__ float stats[2];

#pragma unroll
    for (int off = 32; off; off >>= 1) {
        s  += __shfl_down(s, off);
        sq += __shfl_down(sq, off);
    }
    const int wave = tid >> 6;
    if ((tid & 63) == 0) { red[wave] = s; red[wave + 4] = sq; }
    __syncthreads();
    if (tid == 0) {
        float ts = red[0] + red[1] + red[2] + red[3];
        float tq = red[4] + red[5] + red[6] + red[7];
        float mean = ts / (float)L_;
        float var  = tq / (float)L_ - mean * mean;
        stats[0] = mean;
        stats[1] = rsqrtf(var + EPS);
    }
    __syncthreads();
    const float mean = stats[0], rstd = stats[1];
    p[tid]       = f2bf((x0 - mean) * rstd * g[tid]       + bvec[tid]);
    p[tid + 256] = f2bf((x1 - mean) * rstd * g[tid + 256] + bvec[tid + 256]);
}

// ---------------------------------------------------------------------------
// Flash attention v12 (UNCHANGED -- anchor: 72-81us band, clock-dependent).
// v9 structure + expx() static softmax.
// LDS: 32KB Kdbuf + 32KB Vdbuf + 9KB Pl = 73KB -> 2 blocks/CU.
// ---------------------------------------------------------------------------
#define PPITCH 72

__global__ __launch_bounds__(256)
void flash_attn_kernel(const u16* __restrict__ qbf, const u16* __restrict__ kbf,
                       const u16* __restrict__ vt,
                       const unsigned char* __restrict__ mask,
                       u16* __restrict__ out) {
    const int x    = blockIdx.x;
    const int qgrp = (S_ / 64 - 1) - (x >> 5);   // heavy blocks first
    const int hb   = x & 31;
    const int h    = hb >> 1, b = hb & 1;
    const int tid  = threadIdx.x;
    const int wave = tid >> 6, lane = tid & 63;
    const int l15  = lane & 15, g = lane >> 4;
    const int q0   = qgrp * 64 + wave * 16;      // this wave's 16 queries

    __shared__ __align__(16) u16 Ks[2][64][128];   // 2 x 16 KB, key x d
    __shared__ __align__(16) u16 Vs[2][128][64];   // 2 x 16 KB, d x key
    __shared__ __align__(16) u16 Pl[4][16][PPITCH];

    const u16* kbase = kbf + (size_t)b * S_ * D_ + h * HD_;
    const u16* vbase = vt + (size_t)((b * H_ + h) * HD_) * S_;
    const unsigned char* mbase = mask + b * S_;

    const int kr_l = lane >> 4;          // K: row within 4-row chunk
    const int kb_l = (lane & 15) * 16;   // K: byte within 256B row
    const int vr_l = lane >> 3;          // V: row within 8-row chunk
    const int vb_l = (lane & 7) * 16;    // V: byte within 128B row

    auto STAGE = [&](int bi, int k0s) {
#pragma unroll
        for (int j = 0; j < 4; ++j) {
            const int rr = wave * 16 + j * 4 + kr_l;          // key row 0..63
            gl_lds16(kbase + (size_t)(k0s + rr) * D_ +
                         ((kb_l ^ ((rr & 7) << 4)) >> 1),
                     &Ks[bi][wave * 16 + j * 4][0]);
            const int rv = wave * 32 + j * 8 + vr_l;          // d row 0..127
            gl_lds16(vbase + (size_t)rv * S_ + k0s +
                         ((vb_l ^ ((rv & 7) << 4)) >> 1),
                     &Vs[bi][wave * 32 + j * 8][0]);
        }
    };

    // Q fragments (A-operand): row l15, k = c*32 + g*8 + j
    bf16x8 qf[4];
#pragma unroll
    for (int c = 0; c < 4; ++c)
        qf[c] = *(const bf16x8*)(qbf +
            (size_t)(b * S_ + q0 + l15) * D_ + h * HD_ + c * 32 + g * 8);

    // all-ones bf16 B-fragment for the row-sum MFMA
    bf16x8 ones;
#pragma unroll
    for (int j = 0; j < 8; ++j) ones[j] = (short)0x3f80;  // 1.0f in bf16

    f32x4 o[8];
#pragma unroll
    for (int i = 0; i < 8; ++i) o[i] = (f32x4)0.f;
    f32x4 osum = (f32x4)0.f;

    const int qb  = q0 + 4 * g;
    const int ksw = (l15 & 7) << 4;        // read-side XOR key (bytes)
    const int nt  = qgrp + 1;              // uniform across the block

    STAGE(0, 0);
    __syncthreads();   // implicit vmcnt(0) drain before s_barrier

    for (int kt = 0; kt < nt; ++kt) {
        const int k0  = kt * 64;
        const int cur = kt & 1;
        if (kt + 1 < nt) STAGE(cur ^ 1, k0 + 64);   // prefetch next tile

        // padding mask -> additive bias (static shift, or -inf)
        float nb[4];
#pragma unroll
        for (int cc = 0; cc < 4; ++cc)
            nb[cc] = mbase[k0 + cc * 16 + l15] ? -INFINITY : SCORE_SHIFT;

        // QK^T from LDS: 4 independent accumulation chains of 4 MFMAs
        f32x4 s[4];
#pragma unroll
        for (int cc = 0; cc < 4; ++cc) {
            bf16x8 kf[4];
#pragma unroll
            for (int c = 0; c < 4; ++c)
                kf[c] = *(const bf16x8*)&Ks[cur][cc * 16 + l15]
                    [((c * 64 + g * 16) ^ ksw) >> 1];
            f32x4 t = (f32x4)0.f;
#pragma unroll
            for (int c = 0; c < 4; ++c)
                t = __builtin_amdgcn_mfma_f32_16x16x32_bf16(qf[c], kf[c], t, 0, 0, 0);
            s[cc] = t;
        }

        // scale + shift/padding in one FMA per score
#pragma unroll
        for (int cc = 0; cc < 4; ++cc)
#pragma unroll
            for (int r = 0; r < 4; ++r)
                s[cc][r] = fmaf(s[cc][r], SCORE_SCALE, nb[cc]);

        // causal mask: only the final tile contains keys > query
        if (kt == nt - 1) {
#pragma unroll
            for (int cc = 0; cc < 4; ++cc) {
                const int kk = k0 + cc * 16 + l15;
#pragma unroll
                for (int r = 0; r < 4; ++r)
                    if (kk > qb + r) s[cc][r] = -INFINITY;
            }
        }

        // P = expx(s): C-layout -> LDS -> A-layout (no max, no rescale)
#pragma unroll
        for (int cc = 0; cc < 4; ++cc)
#pragma unroll
            for (int r = 0; r < 4; ++r)
                Pl[wave][4 * g + r][cc * 16 + l15] = f2bf(expx(s[cc][r]));

        const bf16x8 pf0 = *(const bf16x8*)&Pl[wave][l15][g * 8];
        const bf16x8 pf1 = *(const bf16x8*)&Pl[wave][l15][32 + g * 8];

        // PV from LDS over 64 keys + ones-column row-sum accumulation
#pragma unroll
        for (int i = 0; i < 8; ++i) {
            bf16x8 vf0 = *(const bf16x8*)&Vs[cur][16 * i + l15]
                [((g * 16) ^ ksw) >> 1];
            bf16x8 vf1 = *(const bf16x8*)&Vs[cur][16 * i + l15]
                [((g * 16 + 64) ^ ksw) >> 1];
            o[i] = __builtin_amdgcn_mfma_f32_16x16x32_bf16(pf0, vf0, o[i], 0, 0, 0);
            o[i] = __builtin_amdgcn_mfma_f32_16x16x32_bf16(pf1, vf1, o[i], 0, 0, 0);
        }
        osum = __builtin_amdgcn_mfma_f32_16x16x32_bf16(pf0, ones, osum, 0, 0, 0);
        osum = __builtin_amdgcn_mfma_f32_16x16x32_bf16(pf1, ones, osum, 0, 0, 0);

        __syncthreads();   // drains prefetch (vmcnt(0)) + WAR on buf[cur]
    }

    // epilogue: normalize by osum (row-sum of bf16 P, same rows as o) + store
    float inv[4];
#pragma unroll
    for (int r = 0; r < 4; ++r) inv[r] = 1.0f / osum[r];
#pragma unroll
    for (int i = 0; i < 8; ++i)
#pragma unroll
        for (int r = 0; r < 4; ++r)
            out[(size_t)(b * S_ + q0 + 4 * g + r) * D_ +
                h * HD_ + 16 * i + l15] = f2bf(o[i][r] * inv[r]);
}

// ---------------------------------------------------------------------------
extern "C" void kernel_launch(void* const* d_in, const int* in_sizes, int n_in,
                              void* d_out, int out_size, void* d_ws, size_t ws_size,
                              hipStream_t stream) {
    const float* x        = (const float*)d_in[0];
    const unsigned char* mask = (const unsigned char*)d_in[1];
    const float* wq_down  = (const float*)d_in[2];
    const float* bq_down  = (const float*)d_in[3];
    const float* gq_ln    = (const float*)d_in[4];
    const float* bq_ln    = (const float*)d_in[5];
    const float* wq_up    = (const float*)d_in[6];
    const float* bq_up    = (const float*)d_in[7];
    const float* wkv_down = (const float*)d_in[8];
    const float* bkv_down = (const float*)d_in[9];
    const float* gkv_ln   = (const float*)d_in[10];
    const float* bkv_ln   = (const float*)d_in[11];
    const float* wkv_up   = (const float*)d_in[12];
    const float* bkv_up   = (const float*)d_in[13];
    const float* w_out    = (const float*)d_in[14];
    const float* b_out    = (const float*)d_in[15];
    float* out = (float*)d_out;

    // Workspace layout (byte offsets, MB). Total 90 MB.
    //  0-16 : x_bf (dead after down-GEMM) / vt (written by up-GEMM V-epilogue)
    // 16-24 : lat fused [4096][1024] bf16 (dead after up-GEMMs)
    // 16-32 : attn_bf (written by flash; overlays lat + wd_t + wkvu_t, all dead)
    // 24-28 : wd_t fused [1024][2048]
    // 28-32 : wkvu_t   32-34 : wqu_t   34-42 : wout_t
    // 42-58 : q_bf     58-74 : k_bf [4096][2048] (compact K, V fused to vt)
    char* ws = (char*)d_ws;
    u16* x_bf    = (u16*)(ws);
    u16* vt      = (u16*)(ws);
    u16* lat     = (u16*)(ws + (16u << 20));
    u16* attn_bf = (u16*)(ws + (16u << 20));
    u16* wd_t    = (u16*)(ws + (24u << 20));
    u16* wkvu_t  = (u16*)(ws + (28u << 20));
    u16* wqu_t   = (u16*)(ws + (32u << 20));
    u16* wout_t  = (u16*)(ws + (34u << 20));
    u16* q_bf    = (u16*)(ws + (42u << 20));
    u16* k_bf    = (u16*)(ws + (58u << 20));

    const int M = B_ * S_;  // 4096
    dim3 blk(256);

    // prep: x cast + all 5 weight transposes in one launch
    prep_kernel<<<10496, blk, 0, stream>>>(
        wq_down, wkv_down, wq_up, wkv_up, w_out, x,
        wd_t, wqu_t, wkvu_t, wout_t, x_bf);

    // fused down-projection: [M,2048] @ [2048,1024] -> lat (q | kv),
    // BN=64 (2 blk/CU) + BK=128 (8 K-iterations; LDS 48KB, capacity 3 >= 2)
    gemm_mfma_kernel<u16, 64, 128><<<dim3((2 * L_) / 64, M / 128), blk, 0, stream>>>(
        x_bf, wd_t, bq_down, bkv_down, lat,
        M, 2 * L_, D_, D_, 2 * L_, L_);

    // fused LayerNorm over both halves
    layernorm_fused_kernel<<<2 * M, blk, 0, stream>>>(lat, gq_ln, bq_ln, gkv_ln, bkv_ln);

    // merged up-projections: kv-up (with fused V transpose) + q-up, BK=64
    up_gemm_kernel<<<dim3(48, M / 128), blk, 0, stream>>>(
        lat, wkvu_t, wqu_t, bkv_up, bq_up, k_bf, vt, q_bf);

    // Flash attention v12 -> bf16 attn (unchanged anchor)
    flash_attn_kernel<<<dim3((S_ / 64) * H_ * B_), blk, 0, stream>>>(
        q_bf, k_bf, vt, mask, attn_bf);

    // Output projection (fp32 out), BN=128 + BK=128 (16 K-iterations;
    // LDS 64KB, capacity 2 = grid-capped residency -- no occupancy loss)
    gemm_mfma_kernel<float, 128, 128><<<dim3(D_ / 128, M / 128), blk, 0, stream>>>(
        attn_bf, wout_t, b_out, b_out, out,
        M, D_, D_, D_, D_, D_);
}